// Round 19
// baseline (178.038 us; speedup 1.0000x reference)
//
#include <hip/hip_runtime.h>
#include <stdint.h>

typedef unsigned int u32;
typedef unsigned short u16;
typedef __attribute__((ext_vector_type(8))) short v8s;   // 8 bf16 (4 VGPRs)
typedef __attribute__((ext_vector_type(4))) float v4f;   // 4 f32 acc

#define GN_EPS 1e-5f

// ---------- bf16 helpers (intermediates in ws are bf16) ----------
__device__ __forceinline__ float bflo(u32 u){ return __uint_as_float(u << 16); }
__device__ __forceinline__ float bfhi(u32 u){ return __uint_as_float(u & 0xffff0000u); }
__device__ __forceinline__ float bf1(u16 u){ return __uint_as_float((u32)u << 16); }
__device__ __forceinline__ u16 f2bf(float f){
  u32 x = __float_as_uint(f);
  u32 r = (x + 0x7fffu + ((x >> 16) & 1u)) >> 16;   // RNE
  return (u16)r;
}
__device__ __forceinline__ u32 pack2(float a, float b){
  return (u32)f2bf(a) | ((u32)f2bf(b) << 16);
}
__device__ __forceinline__ void unpack8(const uint4 u, float* f){
  f[0]=bflo(u.x); f[1]=bfhi(u.x); f[2]=bflo(u.y); f[3]=bfhi(u.y);
  f[4]=bflo(u.z); f[5]=bfhi(u.z); f[6]=bflo(u.w); f[7]=bfhi(u.w);
}
// load 8 f32, return packed bf16 (4 u32)
__device__ __forceinline__ uint4 loadpack8(const float* __restrict__ p){
  float4 a = *(const float4*)p, b = *(const float4*)(p + 4);
  return make_uint4(pack2(a.x,a.y),pack2(a.z,a.w),pack2(b.x,b.y),pack2(b.z,b.w));
}
__device__ __forceinline__ float dot16(const float* __restrict__ yn,
                                       const float* __restrict__ row){
  float4 W0 = *(const float4*)row;
  float4 W1 = *(const float4*)(row + 4);
  float4 W2 = *(const float4*)(row + 8);
  float4 W3 = *(const float4*)(row + 12);
  float d = 0.f;
  d = fmaf(yn[0],W0.x,d); d = fmaf(yn[1],W0.y,d);
  d = fmaf(yn[2],W0.z,d); d = fmaf(yn[3],W0.w,d);
  d = fmaf(yn[4],W1.x,d); d = fmaf(yn[5],W1.y,d);
  d = fmaf(yn[6],W1.z,d); d = fmaf(yn[7],W1.w,d);
  d = fmaf(yn[8],W2.x,d); d = fmaf(yn[9],W2.y,d);
  d = fmaf(yn[10],W2.z,d); d = fmaf(yn[11],W2.w,d);
  d = fmaf(yn[12],W3.x,d); d = fmaf(yn[13],W3.y,d);
  d = fmaf(yn[14],W3.z,d); d = fmaf(yn[15],W3.w,d);
  return d;
}
__device__ __forceinline__ float rsum16(float v){
  v += __shfl_xor(v, 1);
  v += __shfl_xor(v, 2);
  v += __shfl_xor(v, 4);
  v += __shfl_xor(v, 8);
  return v;
}

// batch accessor: int32 or int64 (little-endian low word)
__device__ __forceinline__ int getb(const int* __restrict__ b, int is64, int i){
  return b[is64 ? 2*i : i];
}

// =====================================================================
// K0: detect batch int-width (parallel).
// =====================================================================
__global__ __launch_bounds__(256) void k_detect(
    const int* __restrict__ batch, int n, int* __restrict__ flags)
{
  int i = blockIdx.x*256 + threadIdx.x;
  int bad = 0;
  if (i < n - 1 && batch[i] > batch[i + 1]) bad = 1;
  if (__builtin_amdgcn_ballot_w64(bad) != 0 && (threadIdx.x & 63) == 0)
    atomicOr(&flags[0], 1);
}

// =====================================================================
// K0b: CSR bounds. bounds[g] = first node of graph g; bounds[B] = N.
// =====================================================================
__global__ __launch_bounds__(256) void k_bounds(
    const int* __restrict__ batch, const int* __restrict__ flags,
    int N, int B, int* __restrict__ bounds)
{
  int i = blockIdx.x*256 + threadIdx.x;
  if (i >= N) return;
  const int is64 = flags[0];
  int b = getb(batch, is64, i);
  int prev = (i == 0) ? -1 : getb(batch, is64, i - 1);
  for (int g = prev + 1; g <= b; g++) bounds[g] = i;
  if (i == N - 1)
    for (int g = b + 1; g <= B; g++) bounds[g] = N;
}

// =====================================================================
// K1 (fused MFMA GEMM + GroupNorm + grouped QKV convs).
// Tile 128 nodes x 64 cols (= 4 complete groups).
// Conv phase: wave w = group w; weights read DIRECT from global
// (wave-uniform addresses -> L2 broadcast; no LDS staging).
// LDS = As 10.2K + Bs 5.1K + ynL 18.5K = 33.8KB -> 4 blocks/CU.
// =====================================================================
__global__ __launch_bounds__(256) void k_prefused(
    const float* __restrict__ x, const float* __restrict__ wpre,
    const float* __restrict__ bpre,
    const float* __restrict__ wq, const float* __restrict__ wk,
    const float* __restrict__ wv,
    u16* __restrict__ qo, u16* __restrict__ ko, u16* __restrict__ vo,
    int N, int nbm)
{
  __shared__ __align__(16) u16 As[128*40];
  __shared__ __align__(16) u16 Bs[64*40];
  __shared__ __align__(16) u16 ynL[128*74];     // 18.5 KB, odd dword stride

  const int t = threadIdx.x;
  const int bm = blockIdx.x % nbm;
  const int bn = blockIdx.x / nbm;              // 0..3
  const int m_base = bm*128, n_base = bn*64;
  const int w = t >> 6, lane = t & 63;
  const int wr = (w >> 1)*64, wc = (w & 1)*32;
  const int fr = lane & 15, fk = lane >> 4;
  const int arow = t >> 1, acol = (t & 1)*16;
  const int brow = t >> 2, bcol = (t & 3)*8;

  v4f acc[4][2];
#pragma unroll
  for (int i = 0; i < 4; i++)
#pragma unroll
    for (int j = 0; j < 2; j++) acc[i][j] = (v4f){0.f,0.f,0.f,0.f};

  for (int k0 = 0; k0 < 256; k0 += 32) {
    __syncthreads();
    {
      int gm = m_base + arow;
      uint4 a0 = make_uint4(0u,0u,0u,0u), a1 = make_uint4(0u,0u,0u,0u);
      if (gm < N) {
        a0 = loadpack8(x + (size_t)gm*256 + k0 + acol);
        a1 = loadpack8(x + (size_t)gm*256 + k0 + acol + 8);
      }
      *(uint4*)&As[arow*40 + acol]     = a0;
      *(uint4*)&As[arow*40 + acol + 8] = a1;
      uint4 bv = loadpack8(wpre + (size_t)(n_base + brow)*256 + k0 + bcol);
      *(uint4*)&Bs[brow*40 + bcol] = bv;
    }
    __syncthreads();
    v8s b0 = *(const v8s*)&Bs[(wc      + fr)*40 + fk*8];
    v8s b1 = *(const v8s*)&Bs[(wc + 16 + fr)*40 + fk*8];
#pragma unroll
    for (int mi = 0; mi < 4; mi++) {
      v8s a = *(const v8s*)&As[(wr + mi*16 + fr)*40 + fk*8];
      acc[mi][0] = __builtin_amdgcn_mfma_f32_16x16x32_bf16(a,b0,acc[mi][0],0,0,0);
      acc[mi][1] = __builtin_amdgcn_mfma_f32_16x16x32_bf16(a,b1,acc[mi][1],0,0,0);
    }
  }

  // ---- epilogue: GroupNorm in-register, yn -> ynL ----
#pragma unroll
  for (int nj = 0; nj < 2; nj++) {
    int col = n_base + wc + nj*16 + fr;
    float bpv = bpre[col];
    int gloc = (w & 1)*2 + nj;                  // group within tile 0..3
#pragma unroll
    for (int mi = 0; mi < 4; mi++) {
#pragma unroll
      for (int r = 0; r < 4; r++) {
        float yv = acc[mi][nj][r] + bpv;
        float s1 = rsum16(yv);
        float s2 = rsum16(yv*yv);
        float mu = s1 * 0.0625f;
        float var = fmaxf(s2*0.0625f - mu*mu, 0.f);
        float ynv = (yv - mu) * rsqrtf(var + GN_EPS);
        int row = wr + mi*16 + fk*4 + r;        // 0..127
        ynL[row*74 + gloc*16 + fr] = f2bf(ynv);
      }
    }
  }
  __syncthreads();   // ynL published

  // ---- conv phase: wave w = group w; weights direct from global ----
  u16* outs[3] = {qo, ko, vo};
  const float* wsrc[3] = {wq, wk, wv};
  const int gl = w;                             // 4 waves, 4 groups
  const int g  = bn*4 + gl;
#pragma unroll
  for (int p = 0; p < 2; p++) {
    int nloc = p*64 + lane;
    int node = m_base + nloc;
    if (node >= N) continue;
    u32 yw[8];
#pragma unroll
    for (int j = 0; j < 8; j++)
      yw[j] = *(const u32*)&ynL[nloc*74 + gl*16 + j*2];
    float yn[16];
#pragma unroll
    for (int j = 0; j < 8; j++) { yn[2*j] = bflo(yw[j]); yn[2*j+1] = bfhi(yw[j]); }
#pragma unroll
    for (int tz = 0; tz < 3; tz++) {
      const float* wg = wsrc[tz] + (size_t)g*512;
#pragma unroll
      for (int s = 0; s < 2; s++) {
        u32 pk[8];
#pragma unroll
        for (int o = 0; o < 16; o++) {
          float d = dot16(yn, wg + (s*16 + o)*16);
          if (tz < 2) d = __expf(d*0.25f);
          if (o & 1) pk[o>>1] |= (u32)f2bf(d) << 16;
          else       pk[o>>1]  = (u32)f2bf(d);
        }
        u16* dst = outs[tz] + (size_t)node*512 + g*32 + s*16;
        *(uint4*)dst       = make_uint4(pk[0],pk[1],pk[2],pk[3]);
        *(uint4*)(dst + 8) = make_uint4(pk[4],pk[5],pk[6],pk[7]);
      }
    }
  }
}

// =====================================================================
// K3 (512 threads, fused, reduction-free): thread (nh, d) owns output
// row KV[nh][d][0:16] and k_sum[nh][d]; accumulates over ALL graph
// nodes. Phase 2: out1 = KV + xres; kv -> LDS bf16. Phase 3: att.
// =====================================================================
__global__ __launch_bounds__(512) void k_segatt(
    const u16* __restrict__ xk, const u16* __restrict__ xv,
    const u16* __restrict__ xq, const float* __restrict__ xres,
    const int* __restrict__ bounds,
    float* __restrict__ out1, u16* __restrict__ att, int N)
{
  __shared__ __align__(16) u16 kvs[32*280];     // 17.5 KB
  __shared__ float kss[32*17];                  // 2.2 KB
  const int b = blockIdx.x, t = threadIdx.x;
  const int lo = bounds[b], hi = bounds[b+1];
  const int nh = t >> 4, d = t & 15;

  float kv[16];
#pragma unroll
  for (int v = 0; v < 16; v++) kv[v] = 0.f;
  float ks = 0.f;

  const size_t koff = (size_t)nh*16 + d;
  const size_t voff = (size_t)nh*16;
  int node = lo;
  for (; node + 1 < hi; node += 2) {
    u16  ka  = xk[(size_t)node*512 + koff];
    uint4 Va0 = *(const uint4*)(xv + (size_t)node*512 + voff);
    uint4 Va1 = *(const uint4*)(xv + (size_t)node*512 + voff + 8);
    u16  kb  = xk[(size_t)(node+1)*512 + koff];
    uint4 Vb0 = *(const uint4*)(xv + (size_t)(node+1)*512 + voff);
    uint4 Vb1 = *(const uint4*)(xv + (size_t)(node+1)*512 + voff + 8);
    float k0 = bf1(ka), k1 = bf1(kb);
    float va[16], vb[16];
    unpack8(Va0, va); unpack8(Va1, va + 8);
    unpack8(Vb0, vb); unpack8(Vb1, vb + 8);
    ks += k0 + k1;
#pragma unroll
    for (int v = 0; v < 16; v++) {
      kv[v] = fmaf(k0, va[v], kv[v]);
      kv[v] = fmaf(k1, vb[v], kv[v]);
    }
  }
  if (node < hi) {
    u16  ka  = xk[(size_t)node*512 + koff];
    uint4 V0 = *(const uint4*)(xv + (size_t)node*512 + voff);
    uint4 V1 = *(const uint4*)(xv + (size_t)node*512 + voff + 8);
    float k0 = bf1(ka);
    float vf[16]; unpack8(V0, vf); unpack8(V1, vf + 8);
    ks += k0;
#pragma unroll
    for (int v = 0; v < 16; v++) kv[v] = fmaf(k0, vf[v], kv[v]);
  }

  kss[nh*17 + d] = ks;

  {
    size_t idx = ((size_t)(b*32 + nh)*16 + d)*16;
    const float* xp = xres + idx;
    float4 X0 = *(const float4*)xp;
    float4 X1 = *(const float4*)(xp + 4);
    float4 X2 = *(const float4*)(xp + 8);
    float4 X3 = *(const float4*)(xp + 12);
    float xf[16] = {X0.x,X0.y,X0.z,X0.w,X1.x,X1.y,X1.z,X1.w,
                    X2.x,X2.y,X2.z,X2.w,X3.x,X3.y,X3.z,X3.w};
    float o[16];
#pragma unroll
    for (int j = 0; j < 16; j++) o[j] = kv[j] + xf[j];
    float* op = out1 + idx;
    *(float4*)op        = make_float4(o[0],o[1],o[2],o[3]);
    *(float4*)(op + 4)  = make_float4(o[4],o[5],o[6],o[7]);
    *(float4*)(op + 8)  = make_float4(o[8],o[9],o[10],o[11]);
    *(float4*)(op + 12) = make_float4(o[12],o[13],o[14],o[15]);
    u16* lp = &kvs[nh*280 + d*16];
    *(uint4*)lp       = make_uint4(pack2(o[0],o[1]),  pack2(o[2],o[3]),
                                   pack2(o[4],o[5]),  pack2(o[6],o[7]));
    *(uint4*)(lp + 8) = make_uint4(pack2(o[8],o[9]),  pack2(o[10],o[11]),
                                   pack2(o[12],o[13]),pack2(o[14],o[15]));
  }
  __syncthreads();

  const int nh2 = t & 31, ns = t >> 5;   // ns 0..15
  for (int n0 = lo; n0 < hi; n0 += 16) {
    int nodei = n0 + ns;
    if (nodei >= hi) continue;
    const u16* qp = xq + (size_t)nodei*512 + nh2*16;
    uint4 Q0 = *(const uint4*)qp;
    uint4 Q1 = *(const uint4*)(qp + 8);
    float q[16]; unpack8(Q0, q); unpack8(Q1, q + 8);
    const float* ksp = &kss[nh2*17];
    float denom = 0.f;
#pragma unroll
    for (int i = 0; i < 16; i++) denom = fmaf(q[i], ksp[i], denom);
    float inv = 1.0f / fmaxf(denom, 1e-20f);
    float a[16];
#pragma unroll
    for (int v = 0; v < 16; v++) a[v] = 0.f;
    const u16* kvp = &kvs[nh2*280];
#pragma unroll
    for (int h = 0; h < 16; h++) {
      float qh = q[h] * inv;
      uint4 W0 = *(const uint4*)(kvp + h*16);
      uint4 W1 = *(const uint4*)(kvp + h*16 + 8);
      float wv2[16]; unpack8(W0, wv2); unpack8(W1, wv2 + 8);
#pragma unroll
      for (int v = 0; v < 16; v++) a[v] = fmaf(qh, wv2[v], a[v]);
    }
    u32 p[8];
#pragma unroll
    for (int j = 0; j < 8; j++) p[j] = pack2(a[2*j], a[2*j+1]);
    u16* dst = att + (size_t)nodei*512 + nh2*16;
    *(uint4*)dst       = make_uint4(p[0],p[1],p[2],p[3]);
    *(uint4*)(dst + 8) = make_uint4(p[4],p[5],p[6],p[7]);
  }
}

// =====================================================================
// K5 (MFMA): out0 = exp(log_scale) * (att @ w_post^T + b_post), K=512.
// Tile 128x128 (2 col-blocks), wave tile 64x64, acc 4x4.
// =====================================================================
__global__ __launch_bounds__(256) void k_post(
    const u16* __restrict__ att, const float* __restrict__ wpost,
    const float* __restrict__ bpost, const float* __restrict__ ls,
    float* __restrict__ out0, int N, int nbm)
{
  __shared__ __align__(16) u16 As[128*40];
  __shared__ __align__(16) u16 Bs[128*40];
  const int t = threadIdx.x;
  const int bm = blockIdx.x % nbm;
  const int bn = blockIdx.x / nbm;          // 0..1
  const int m_base = bm*128, n_base = bn*128;
  const int w = t >> 6, lane = t & 63;
  const int wr = (w >> 1)*64, wc = (w & 1)*64;
  const int fr = lane & 15, fk = lane >> 4;
  const int arow = t >> 1, acol = (t & 1)*16;

  v4f acc[4][4];
#pragma unroll
  for (int i = 0; i < 4; i++)
#pragma unroll
    for (int j = 0; j < 4; j++) acc[i][j] = (v4f){0.f,0.f,0.f,0.f};

  for (int k0 = 0; k0 < 512; k0 += 32) {
    __syncthreads();
    {
      int gm = m_base + arow;
      uint4 a0 = make_uint4(0u,0u,0u,0u), a1 = make_uint4(0u,0u,0u,0u);
      if (gm < N) {
        a0 = *(const uint4*)(att + (size_t)gm*512 + k0 + acol);
        a1 = *(const uint4*)(att + (size_t)gm*512 + k0 + acol + 8);
      }
      *(uint4*)&As[arow*40 + acol]     = a0;
      *(uint4*)&As[arow*40 + acol + 8] = a1;
      uint4 b0 = loadpack8(wpost + (size_t)(n_base + arow)*512 + k0 + acol);
      uint4 b1 = loadpack8(wpost + (size_t)(n_base + arow)*512 + k0 + acol + 8);
      *(uint4*)&Bs[arow*40 + acol]     = b0;
      *(uint4*)&Bs[arow*40 + acol + 8] = b1;
    }
    __syncthreads();
    v8s bfr[4];
#pragma unroll
    for (int j = 0; j < 4; j++)
      bfr[j] = *(const v8s*)&Bs[(wc + j*16 + fr)*40 + fk*8];
#pragma unroll
    for (int mi = 0; mi < 4; mi++) {
      v8s a = *(const v8s*)&As[(wr + mi*16 + fr)*40 + fk*8];
#pragma unroll
      for (int j = 0; j < 4; j++)
        acc[mi][j] = __builtin_amdgcn_mfma_f32_16x16x32_bf16(a,bfr[j],acc[mi][j],0,0,0);
    }
  }
#pragma unroll
  for (int nj = 0; nj < 4; nj++) {
    int col = n_base + wc + nj*16 + fr;
    float bpv = bpost[col];
    float e   = __expf(ls[col]);
#pragma unroll
    for (int mi = 0; mi < 4; mi++) {
#pragma unroll
      for (int r = 0; r < 4; r++) {
        int row = m_base + wr + mi*16 + fk*4 + r;
        if (row < N) out0[(size_t)row*256 + col] = e*(acc[mi][nj][r] + bpv);
      }
    }
  }
}

// =====================================================================
extern "C" void kernel_launch(void* const* d_in, const int* in_sizes, int n_in,
                              void* d_out, int out_size, void* d_ws, size_t ws_size,
                              hipStream_t stream)
{
  const float* x     = (const float*)d_in[0];
  const float* xres  = (const float*)d_in[1];
  const int*   batch = (const int*)d_in[2];
  const float* wpre  = (const float*)d_in[4];
  const float* bpre  = (const float*)d_in[5];
  const float* wq    = (const float*)d_in[6];
  const float* wk    = (const float*)d_in[7];
  const float* wv    = (const float*)d_in[8];
  const float* wpost = (const float*)d_in[9];
  const float* bpost = (const float*)d_in[10];
  const float* ls    = (const float*)d_in[11];

  const int N = in_sizes[0] / 256;     // 20000 nodes
  const int B = in_sizes[1] / 8192;    // 1024 graphs
  const int nbm = (N + 127) / 128;     // 157 row tiles
  const int nchunk = (N + 255) / 256;  // 79 node chunks

  char* ws = (char*)d_ws;
  size_t off = 0;
  int*   flags  = (int*)(ws + off); off += 256;
  int*   bounds = (int*)(ws + off); off += ((size_t)B + 64) * 4;
  u16*   att    = (u16*)(ws + off);  off += (size_t)N * 1024;
  u16*   q      = (u16*)(ws + off);  off += (size_t)N * 1024;
  u16*   kten   = (u16*)(ws + off);  off += (size_t)N * 1024;
  u16*   vten   = (u16*)(ws + off);  off += (size_t)N * 1024;

  float* out0 = (float*)d_out;
  float* out1 = out0 + (size_t)N * 256;

  hipMemsetAsync(flags, 0, 4, stream);
  k_detect  <<<nchunk,        256, 0, stream>>>(batch, N, flags);
  k_bounds  <<<nchunk,        256, 0, stream>>>(batch, flags, N, B, bounds);
  k_prefused<<<nbm * 4,       256, 0, stream>>>(x, wpre, bpre, wq, wk, wv,
                                                q, kten, vten, N, nbm);
  k_segatt  <<<B,             512, 0, stream>>>(kten, vten, q, xres, bounds,
                                                out1, att, N);
  k_post    <<<nbm * 2,       256, 0, stream>>>(att, wpost, bpost, ls, out0, N, nbm);
}

// Round 20
// 157.685 us; speedup vs baseline: 1.1291x; 1.1291x over previous
//
#include <hip/hip_runtime.h>
#include <stdint.h>

typedef unsigned int u32;
typedef unsigned short u16;
typedef __attribute__((ext_vector_type(8))) short v8s;   // 8 bf16 (4 VGPRs)
typedef __attribute__((ext_vector_type(4))) float v4f;   // 4 f32 acc

#define GN_EPS 1e-5f

// ---------- bf16 helpers (intermediates in ws are bf16) ----------
__device__ __forceinline__ float bflo(u32 u){ return __uint_as_float(u << 16); }
__device__ __forceinline__ float bfhi(u32 u){ return __uint_as_float(u & 0xffff0000u); }
__device__ __forceinline__ float bf1(u16 u){ return __uint_as_float((u32)u << 16); }
__device__ __forceinline__ u16 f2bf(float f){
  u32 x = __float_as_uint(f);
  u32 r = (x + 0x7fffu + ((x >> 16) & 1u)) >> 16;   // RNE
  return (u16)r;
}
__device__ __forceinline__ u32 pack2(float a, float b){
  return (u32)f2bf(a) | ((u32)f2bf(b) << 16);
}
__device__ __forceinline__ void unpack8(const uint4 u, float* f){
  f[0]=bflo(u.x); f[1]=bfhi(u.x); f[2]=bflo(u.y); f[3]=bfhi(u.y);
  f[4]=bflo(u.z); f[5]=bfhi(u.z); f[6]=bflo(u.w); f[7]=bfhi(u.w);
}
// load 8 f32, return packed bf16 (4 u32)
__device__ __forceinline__ uint4 loadpack8(const float* __restrict__ p){
  float4 a = *(const float4*)p, b = *(const float4*)(p + 4);
  return make_uint4(pack2(a.x,a.y),pack2(a.z,a.w),pack2(b.x,b.y),pack2(b.z,b.w));
}
// dot of 16 yn values with a bf16 weight row (8 u32, wave-uniform)
__device__ __forceinline__ float dot16h(const float* __restrict__ yn,
                                        const u16* __restrict__ row){
  const u32* rw = (const u32*)row;
  float d = 0.f;
#pragma unroll
  for (int j = 0; j < 8; j++) {
    u32 wd = rw[j];
    d = fmaf(yn[2*j],   bflo(wd), d);
    d = fmaf(yn[2*j+1], bfhi(wd), d);
  }
  return d;
}
__device__ __forceinline__ float rsum16(float v){
  v += __shfl_xor(v, 1);
  v += __shfl_xor(v, 2);
  v += __shfl_xor(v, 4);
  v += __shfl_xor(v, 8);
  return v;
}

// batch accessor: int32 or int64 (little-endian low word)
__device__ __forceinline__ int getb(const int* __restrict__ b, int is64, int i){
  return b[is64 ? 2*i : i];
}

// =====================================================================
// K0: detect batch int-width (parallel).
// =====================================================================
__global__ __launch_bounds__(256) void k_detect(
    const int* __restrict__ batch, int n, int* __restrict__ flags)
{
  int i = blockIdx.x*256 + threadIdx.x;
  int bad = 0;
  if (i < n - 1 && batch[i] > batch[i + 1]) bad = 1;
  if (__builtin_amdgcn_ballot_w64(bad) != 0 && (threadIdx.x & 63) == 0)
    atomicOr(&flags[0], 1);
}

// =====================================================================
// K0b: CSR bounds. bounds[g] = first node of graph g; bounds[B] = N.
// =====================================================================
__global__ __launch_bounds__(256) void k_bounds(
    const int* __restrict__ batch, const int* __restrict__ flags,
    int N, int B, int* __restrict__ bounds)
{
  int i = blockIdx.x*256 + threadIdx.x;
  if (i >= N) return;
  const int is64 = flags[0];
  int b = getb(batch, is64, i);
  int prev = (i == 0) ? -1 : getb(batch, is64, i - 1);
  for (int g = prev + 1; g <= b; g++) bounds[g] = i;
  if (i == N - 1)
    for (int g = b + 1; g <= B; g++) bounds[g] = N;
}

// =====================================================================
// K1 (fused MFMA GEMM + GroupNorm + grouped QKV convs).
// Tile 128 nodes x 64 cols (= 4 complete groups).
// Conv weights staged in LDS as bf16 (12.5K, fits inside As/Bs union)
// -> total LDS 33.9KB -> 4 blocks/CU. Conv phase: wave w = group w
// (wave-uniform broadcast reads). ynL rows 74 u16 (odd dword stride).
// =====================================================================
__global__ __launch_bounds__(256) void k_prefused(
    const float* __restrict__ x, const float* __restrict__ wpre,
    const float* __restrict__ bpre,
    const float* __restrict__ wq, const float* __restrict__ wk,
    const float* __restrict__ wv,
    u16* __restrict__ qo, u16* __restrict__ ko, u16* __restrict__ vo,
    int N, int nbm)
{
  __shared__ __align__(16) char SMEM[15360];    // As+Bs (15.4K) / wLh (12.5K)
  __shared__ __align__(16) u16 ynL[128*74];     // 18.5 KB
  u16* As  = (u16*)SMEM;                        // 128*40
  u16* Bs  = (u16*)(SMEM + 128*40*2);           // 64*40
  u16* wLh = (u16*)SMEM;                        // 3*2080 u16 after barrier

  const int t = threadIdx.x;
  const int bm = blockIdx.x % nbm;
  const int bn = blockIdx.x / nbm;              // 0..3
  const int m_base = bm*128, n_base = bn*64;
  const int w = t >> 6, lane = t & 63;
  const int wr = (w >> 1)*64, wc = (w & 1)*32;
  const int fr = lane & 15, fk = lane >> 4;
  const int arow = t >> 1, acol = (t & 1)*16;
  const int brow = t >> 2, bcol = (t & 3)*8;

  v4f acc[4][2];
#pragma unroll
  for (int i = 0; i < 4; i++)
#pragma unroll
    for (int j = 0; j < 2; j++) acc[i][j] = (v4f){0.f,0.f,0.f,0.f};

  for (int k0 = 0; k0 < 256; k0 += 32) {
    __syncthreads();
    {
      int gm = m_base + arow;
      uint4 a0 = make_uint4(0u,0u,0u,0u), a1 = make_uint4(0u,0u,0u,0u);
      if (gm < N) {
        a0 = loadpack8(x + (size_t)gm*256 + k0 + acol);
        a1 = loadpack8(x + (size_t)gm*256 + k0 + acol + 8);
      }
      *(uint4*)&As[arow*40 + acol]     = a0;
      *(uint4*)&As[arow*40 + acol + 8] = a1;
      uint4 bv = loadpack8(wpre + (size_t)(n_base + brow)*256 + k0 + bcol);
      *(uint4*)&Bs[brow*40 + bcol] = bv;
    }
    __syncthreads();
    v8s b0 = *(const v8s*)&Bs[(wc      + fr)*40 + fk*8];
    v8s b1 = *(const v8s*)&Bs[(wc + 16 + fr)*40 + fk*8];
#pragma unroll
    for (int mi = 0; mi < 4; mi++) {
      v8s a = *(const v8s*)&As[(wr + mi*16 + fr)*40 + fk*8];
      acc[mi][0] = __builtin_amdgcn_mfma_f32_16x16x32_bf16(a,b0,acc[mi][0],0,0,0);
      acc[mi][1] = __builtin_amdgcn_mfma_f32_16x16x32_bf16(a,b1,acc[mi][1],0,0,0);
    }
  }

  // ---- epilogue: GroupNorm in-register, yn -> ynL ----
#pragma unroll
  for (int nj = 0; nj < 2; nj++) {
    int col = n_base + wc + nj*16 + fr;
    float bpv = bpre[col];
    int gloc = (w & 1)*2 + nj;                  // group within tile 0..3
#pragma unroll
    for (int mi = 0; mi < 4; mi++) {
#pragma unroll
      for (int r = 0; r < 4; r++) {
        float yv = acc[mi][nj][r] + bpv;
        float s1 = rsum16(yv);
        float s2 = rsum16(yv*yv);
        float mu = s1 * 0.0625f;
        float var = fmaxf(s2*0.0625f - mu*mu, 0.f);
        float ynv = (yv - mu) * rsqrtf(var + GN_EPS);
        int row = wr + mi*16 + fk*4 + r;        // 0..127
        ynL[row*74 + gloc*16 + fr] = f2bf(ynv);
      }
    }
  }
  __syncthreads();   // MFMA LDS reads done; ynL published

  // ---- stage qkv weights (bf16) for this tile's 4 groups ----
  {
    const float* srcs[3] = {wq, wk, wv};
    u32* wLw = (u32*)wLh;
#pragma unroll
    for (int tz = 0; tz < 3; tz++) {
      for (int i = t; i < 1024; i += 256) {       // 256 f32-pairs per group
        int gi = i >> 8, rp = i & 255;
        const float* s = srcs[tz] + ((size_t)(bn*4 + gi))*512 + rp*2;
        wLw[tz*1040 + gi*260 + rp] = pack2(s[0], s[1]);
      }
    }
  }
  __syncthreads();

  // ---- conv phase: wave w = group w (wave-uniform bf16 weights) ----
  u16* outs[3] = {qo, ko, vo};
  const int gl = w;                             // 4 waves, 4 groups
  const int g  = bn*4 + gl;
#pragma unroll
  for (int p = 0; p < 2; p++) {
    int nloc = p*64 + lane;
    int node = m_base + nloc;
    if (node >= N) continue;
    u32 yw[8];
#pragma unroll
    for (int j = 0; j < 8; j++)
      yw[j] = *(const u32*)&ynL[nloc*74 + gl*16 + j*2];
    float yn[16];
#pragma unroll
    for (int j = 0; j < 8; j++) { yn[2*j] = bflo(yw[j]); yn[2*j+1] = bfhi(yw[j]); }
#pragma unroll
    for (int tz = 0; tz < 3; tz++) {
      const u16* wg = &wLh[tz*2080 + gl*520];
#pragma unroll
      for (int s = 0; s < 2; s++) {
        u32 pk[8];
#pragma unroll
        for (int o = 0; o < 16; o++) {
          float d = dot16h(yn, wg + (s*16 + o)*16);
          if (tz < 2) d = __expf(d*0.25f);
          if (o & 1) pk[o>>1] |= (u32)f2bf(d) << 16;
          else       pk[o>>1]  = (u32)f2bf(d);
        }
        u16* dst = outs[tz] + (size_t)node*512 + g*32 + s*16;
        *(uint4*)dst       = make_uint4(pk[0],pk[1],pk[2],pk[3]);
        *(uint4*)(dst + 8) = make_uint4(pk[4],pk[5],pk[6],pk[7]);
      }
    }
  }
}

// =====================================================================
// K3 (512 threads, fused, reduction-free): thread (nh, d) owns output
// row KV[nh][d][0:16] and k_sum[nh][d]; accumulates over ALL graph
// nodes. Phase 2: out1 = KV + xres; kv -> LDS bf16. Phase 3: att.
// =====================================================================
__global__ __launch_bounds__(512) void k_segatt(
    const u16* __restrict__ xk, const u16* __restrict__ xv,
    const u16* __restrict__ xq, const float* __restrict__ xres,
    const int* __restrict__ bounds,
    float* __restrict__ out1, u16* __restrict__ att, int N)
{
  __shared__ __align__(16) u16 kvs[32*280];     // 17.5 KB
  __shared__ float kss[32*17];                  // 2.2 KB
  const int b = blockIdx.x, t = threadIdx.x;
  const int lo = bounds[b], hi = bounds[b+1];
  const int nh = t >> 4, d = t & 15;

  float kv[16];
#pragma unroll
  for (int v = 0; v < 16; v++) kv[v] = 0.f;
  float ks = 0.f;

  const size_t koff = (size_t)nh*16 + d;
  const size_t voff = (size_t)nh*16;
  int node = lo;
  for (; node + 1 < hi; node += 2) {
    u16  ka  = xk[(size_t)node*512 + koff];
    uint4 Va0 = *(const uint4*)(xv + (size_t)node*512 + voff);
    uint4 Va1 = *(const uint4*)(xv + (size_t)node*512 + voff + 8);
    u16  kb  = xk[(size_t)(node+1)*512 + koff];
    uint4 Vb0 = *(const uint4*)(xv + (size_t)(node+1)*512 + voff);
    uint4 Vb1 = *(const uint4*)(xv + (size_t)(node+1)*512 + voff + 8);
    float k0 = bf1(ka), k1 = bf1(kb);
    float va[16], vb[16];
    unpack8(Va0, va); unpack8(Va1, va + 8);
    unpack8(Vb0, vb); unpack8(Vb1, vb + 8);
    ks += k0 + k1;
#pragma unroll
    for (int v = 0; v < 16; v++) {
      kv[v] = fmaf(k0, va[v], kv[v]);
      kv[v] = fmaf(k1, vb[v], kv[v]);
    }
  }
  if (node < hi) {
    u16  ka  = xk[(size_t)node*512 + koff];
    uint4 V0 = *(const uint4*)(xv + (size_t)node*512 + voff);
    uint4 V1 = *(const uint4*)(xv + (size_t)node*512 + voff + 8);
    float k0 = bf1(ka);
    float vf[16]; unpack8(V0, vf); unpack8(V1, vf + 8);
    ks += k0;
#pragma unroll
    for (int v = 0; v < 16; v++) kv[v] = fmaf(k0, vf[v], kv[v]);
  }

  kss[nh*17 + d] = ks;

  {
    size_t idx = ((size_t)(b*32 + nh)*16 + d)*16;
    const float* xp = xres + idx;
    float4 X0 = *(const float4*)xp;
    float4 X1 = *(const float4*)(xp + 4);
    float4 X2 = *(const float4*)(xp + 8);
    float4 X3 = *(const float4*)(xp + 12);
    float xf[16] = {X0.x,X0.y,X0.z,X0.w,X1.x,X1.y,X1.z,X1.w,
                    X2.x,X2.y,X2.z,X2.w,X3.x,X3.y,X3.z,X3.w};
    float o[16];
#pragma unroll
    for (int j = 0; j < 16; j++) o[j] = kv[j] + xf[j];
    float* op = out1 + idx;
    *(float4*)op        = make_float4(o[0],o[1],o[2],o[3]);
    *(float4*)(op + 4)  = make_float4(o[4],o[5],o[6],o[7]);
    *(float4*)(op + 8)  = make_float4(o[8],o[9],o[10],o[11]);
    *(float4*)(op + 12) = make_float4(o[12],o[13],o[14],o[15]);
    u16* lp = &kvs[nh*280 + d*16];
    *(uint4*)lp       = make_uint4(pack2(o[0],o[1]),  pack2(o[2],o[3]),
                                   pack2(o[4],o[5]),  pack2(o[6],o[7]));
    *(uint4*)(lp + 8) = make_uint4(pack2(o[8],o[9]),  pack2(o[10],o[11]),
                                   pack2(o[12],o[13]),pack2(o[14],o[15]));
  }
  __syncthreads();

  const int nh2 = t & 31, ns = t >> 5;   // ns 0..15
  for (int n0 = lo; n0 < hi; n0 += 16) {
    int nodei = n0 + ns;
    if (nodei >= hi) continue;
    const u16* qp = xq + (size_t)nodei*512 + nh2*16;
    uint4 Q0 = *(const uint4*)qp;
    uint4 Q1 = *(const uint4*)(qp + 8);
    float q[16]; unpack8(Q0, q); unpack8(Q1, q + 8);
    const float* ksp = &kss[nh2*17];
    float denom = 0.f;
#pragma unroll
    for (int i = 0; i < 16; i++) denom = fmaf(q[i], ksp[i], denom);
    float inv = 1.0f / fmaxf(denom, 1e-20f);
    float a[16];
#pragma unroll
    for (int v = 0; v < 16; v++) a[v] = 0.f;
    const u16* kvp = &kvs[nh2*280];
#pragma unroll
    for (int h = 0; h < 16; h++) {
      float qh = q[h] * inv;
      uint4 W0 = *(const uint4*)(kvp + h*16);
      uint4 W1 = *(const uint4*)(kvp + h*16 + 8);
      float wv2[16]; unpack8(W0, wv2); unpack8(W1, wv2 + 8);
#pragma unroll
      for (int v = 0; v < 16; v++) a[v] = fmaf(qh, wv2[v], a[v]);
    }
    u32 p[8];
#pragma unroll
    for (int j = 0; j < 8; j++) p[j] = pack2(a[2*j], a[2*j+1]);
    u16* dst = att + (size_t)nodei*512 + nh2*16;
    *(uint4*)dst       = make_uint4(p[0],p[1],p[2],p[3]);
    *(uint4*)(dst + 8) = make_uint4(p[4],p[5],p[6],p[7]);
  }
}

// =====================================================================
// K5 (MFMA): out0 = exp(log_scale) * (att @ w_post^T + b_post), K=512.
// Tile 128x64 (round-18 verified version).
// =====================================================================
__global__ __launch_bounds__(256) void k_post(
    const u16* __restrict__ att, const float* __restrict__ wpost,
    const float* __restrict__ bpost, const float* __restrict__ ls,
    float* __restrict__ out0, int N, int nbm)
{
  __shared__ __align__(16) u16 As[128*40];
  __shared__ __align__(16) u16 Bs[64*40];
  const int t = threadIdx.x;
  const int bm = blockIdx.x % nbm;
  const int bn = blockIdx.x / nbm;          // 0..3
  const int m_base = bm*128, n_base = bn*64;
  const int w = t >> 6, lane = t & 63;
  const int wr = (w >> 1)*64, wc = (w & 1)*32;
  const int fr = lane & 15, fk = lane >> 4;
  const int arow = t >> 1, acol = (t & 1)*16;
  const int brow = t >> 2, bcol = (t & 3)*8;

  v4f acc[4][2];
#pragma unroll
  for (int i = 0; i < 4; i++)
#pragma unroll
    for (int j = 0; j < 2; j++) acc[i][j] = (v4f){0.f,0.f,0.f,0.f};

  for (int k0 = 0; k0 < 512; k0 += 32) {
    __syncthreads();
    {
      int gm = m_base + arow;
      uint4 a0 = make_uint4(0u,0u,0u,0u), a1 = make_uint4(0u,0u,0u,0u);
      if (gm < N) {
        a0 = *(const uint4*)(att + (size_t)gm*512 + k0 + acol);
        a1 = *(const uint4*)(att + (size_t)gm*512 + k0 + acol + 8);
      }
      *(uint4*)&As[arow*40 + acol]     = a0;
      *(uint4*)&As[arow*40 + acol + 8] = a1;
      uint4 bv = loadpack8(wpost + (size_t)(n_base + brow)*512 + k0 + bcol);
      *(uint4*)&Bs[brow*40 + bcol] = bv;
    }
    __syncthreads();
    v8s b0 = *(const v8s*)&Bs[(wc      + fr)*40 + fk*8];
    v8s b1 = *(const v8s*)&Bs[(wc + 16 + fr)*40 + fk*8];
#pragma unroll
    for (int mi = 0; mi < 4; mi++) {
      v8s a = *(const v8s*)&As[(wr + mi*16 + fr)*40 + fk*8];
      acc[mi][0] = __builtin_amdgcn_mfma_f32_16x16x32_bf16(a,b0,acc[mi][0],0,0,0);
      acc[mi][1] = __builtin_amdgcn_mfma_f32_16x16x32_bf16(a,b1,acc[mi][1],0,0,0);
    }
  }
#pragma unroll
  for (int nj = 0; nj < 2; nj++) {
    int col = n_base + wc + nj*16 + fr;
    float bpv = bpost[col];
    float e   = __expf(ls[col]);
#pragma unroll
    for (int mi = 0; mi < 4; mi++) {
#pragma unroll
      for (int r = 0; r < 4; r++) {
        int row = m_base + wr + mi*16 + fk*4 + r;
        if (row < N) out0[(size_t)row*256 + col] = e*(acc[mi][nj][r] + bpv);
      }
    }
  }
}

// =====================================================================
extern "C" void kernel_launch(void* const* d_in, const int* in_sizes, int n_in,
                              void* d_out, int out_size, void* d_ws, size_t ws_size,
                              hipStream_t stream)
{
  const float* x     = (const float*)d_in[0];
  const float* xres  = (const float*)d_in[1];
  const int*   batch = (const int*)d_in[2];
  const float* wpre  = (const float*)d_in[4];
  const float* bpre  = (const float*)d_in[5];
  const float* wq    = (const float*)d_in[6];
  const float* wk    = (const float*)d_in[7];
  const float* wv    = (const float*)d_in[8];
  const float* wpost = (const float*)d_in[9];
  const float* bpost = (const float*)d_in[10];
  const float* ls    = (const float*)d_in[11];

  const int N = in_sizes[0] / 256;     // 20000 nodes
  const int B = in_sizes[1] / 8192;    // 1024 graphs
  const int nbm = (N + 127) / 128;     // 157 row tiles
  const int nchunk = (N + 255) / 256;  // 79 node chunks

  char* ws = (char*)d_ws;
  size_t off = 0;
  int*   flags  = (int*)(ws + off); off += 256;
  int*   bounds = (int*)(ws + off); off += ((size_t)B + 64) * 4;
  u16*   att    = (u16*)(ws + off);  off += (size_t)N * 1024;
  u16*   q      = (u16*)(ws + off);  off += (size_t)N * 1024;
  u16*   kten   = (u16*)(ws + off);  off += (size_t)N * 1024;
  u16*   vten   = (u16*)(ws + off);  off += (size_t)N * 1024;

  float* out0 = (float*)d_out;
  float* out1 = out0 + (size_t)N * 256;

  hipMemsetAsync(flags, 0, 4, stream);
  k_detect  <<<nchunk,        256, 0, stream>>>(batch, N, flags);
  k_bounds  <<<nchunk,        256, 0, stream>>>(batch, flags, N, B, bounds);
  k_prefused<<<nbm * 4,       256, 0, stream>>>(x, wpre, bpre, wq, wk, wv,
                                                q, kten, vten, N, nbm);
  k_segatt  <<<B,             512, 0, stream>>>(kten, vten, q, xres, bounds,
                                                out1, att, N);
  k_post    <<<nbm * 4,       256, 0, stream>>>(att, wpost, bpost, ls, out0, N, nbm);
}

// Round 21
// 128.387 us; speedup vs baseline: 1.3867x; 1.2282x over previous
//
#include <hip/hip_runtime.h>
#include <stdint.h>

typedef unsigned int u32;
typedef unsigned short u16;
typedef __attribute__((ext_vector_type(8))) short v8s;   // 8 bf16 (4 VGPRs)
typedef __attribute__((ext_vector_type(4))) float v4f;   // 4 f32 acc

#define GN_EPS 1e-5f

// ---------- bf16 helpers (intermediates in ws are bf16) ----------
__device__ __forceinline__ float bflo(u32 u){ return __uint_as_float(u << 16); }
__device__ __forceinline__ float bfhi(u32 u){ return __uint_as_float(u & 0xffff0000u); }
__device__ __forceinline__ float bf1(u16 u){ return __uint_as_float((u32)u << 16); }
__device__ __forceinline__ u16 f2bf(float f){
  u32 x = __float_as_uint(f);
  u32 r = (x + 0x7fffu + ((x >> 16) & 1u)) >> 16;   // RNE
  return (u16)r;
}
__device__ __forceinline__ u32 pack2(float a, float b){
  return (u32)f2bf(a) | ((u32)f2bf(b) << 16);
}
__device__ __forceinline__ void unpack8(const uint4 u, float* f){
  f[0]=bflo(u.x); f[1]=bfhi(u.x); f[2]=bflo(u.y); f[3]=bfhi(u.y);
  f[4]=bflo(u.z); f[5]=bfhi(u.z); f[6]=bflo(u.w); f[7]=bfhi(u.w);
}
// load 8 f32, return packed bf16 (4 u32)
__device__ __forceinline__ uint4 loadpack8(const float* __restrict__ p){
  float4 a = *(const float4*)p, b = *(const float4*)(p + 4);
  return make_uint4(pack2(a.x,a.y),pack2(a.z,a.w),pack2(b.x,b.y),pack2(b.z,b.w));
}
__device__ __forceinline__ float dot16(const float* __restrict__ yn,
                                       const float* __restrict__ row){
  float4 W0 = *(const float4*)row;
  float4 W1 = *(const float4*)(row + 4);
  float4 W2 = *(const float4*)(row + 8);
  float4 W3 = *(const float4*)(row + 12);
  float d = 0.f;
  d = fmaf(yn[0],W0.x,d); d = fmaf(yn[1],W0.y,d);
  d = fmaf(yn[2],W0.z,d); d = fmaf(yn[3],W0.w,d);
  d = fmaf(yn[4],W1.x,d); d = fmaf(yn[5],W1.y,d);
  d = fmaf(yn[6],W1.z,d); d = fmaf(yn[7],W1.w,d);
  d = fmaf(yn[8],W2.x,d); d = fmaf(yn[9],W2.y,d);
  d = fmaf(yn[10],W2.z,d); d = fmaf(yn[11],W2.w,d);
  d = fmaf(yn[12],W3.x,d); d = fmaf(yn[13],W3.y,d);
  d = fmaf(yn[14],W3.z,d); d = fmaf(yn[15],W3.w,d);
  return d;
}
__device__ __forceinline__ float rsum16(float v){
  v += __shfl_xor(v, 1);
  v += __shfl_xor(v, 2);
  v += __shfl_xor(v, 4);
  v += __shfl_xor(v, 8);
  return v;
}

// batch accessor: int32 or int64 (little-endian low word)
__device__ __forceinline__ int getb(const int* __restrict__ b, int is64, int i){
  return b[is64 ? 2*i : i];
}

// =====================================================================
// K0: detect batch int-width (parallel).
// =====================================================================
__global__ __launch_bounds__(256) void k_detect(
    const int* __restrict__ batch, int n, int* __restrict__ flags)
{
  int i = blockIdx.x*256 + threadIdx.x;
  int bad = 0;
  if (i < n - 1 && batch[i] > batch[i + 1]) bad = 1;
  if (__builtin_amdgcn_ballot_w64(bad) != 0 && (threadIdx.x & 63) == 0)
    atomicOr(&flags[0], 1);
}

// =====================================================================
// K0b: CSR bounds. bounds[g] = first node of graph g; bounds[B] = N.
// =====================================================================
__global__ __launch_bounds__(256) void k_bounds(
    const int* __restrict__ batch, const int* __restrict__ flags,
    int N, int B, int* __restrict__ bounds)
{
  int i = blockIdx.x*256 + threadIdx.x;
  if (i >= N) return;
  const int is64 = flags[0];
  int b = getb(batch, is64, i);
  int prev = (i == 0) ? -1 : getb(batch, is64, i - 1);
  for (int g = prev + 1; g <= b; g++) bounds[g] = i;
  if (i == N - 1)
    for (int g = b + 1; g <= B; g++) bounds[g] = N;
}

// =====================================================================
// K1 (fused MFMA GEMM + GroupNorm + grouped QKV convs).
// Tile 128 nodes x 64 cols (= 4 complete groups).
// Conv phase: wave w = group w (wave-uniform weight broadcast);
// ynL rows padded to 74 u16 (stride-5 banks -> 2-way = free).
// =====================================================================
__global__ __launch_bounds__(256) void k_prefused(
    const float* __restrict__ x, const float* __restrict__ wpre,
    const float* __restrict__ bpre,
    const float* __restrict__ wq, const float* __restrict__ wk,
    const float* __restrict__ wv,
    u16* __restrict__ qo, u16* __restrict__ ko, u16* __restrict__ vo,
    int N, int nbm)
{
  __shared__ __align__(16) char SMEM[25600];    // As/Bs (15.3K) then wL (25K)
  __shared__ __align__(16) u16 ynL[128*74];     // 18.5 KB
  u16* As = (u16*)SMEM;                         // 128*40
  u16* Bs = (u16*)(SMEM + 128*40*2);            // 64*40
  float* wL = (float*)SMEM;                     // 3*2080 f32 after barrier

  const int t = threadIdx.x;
  const int bm = blockIdx.x % nbm;
  const int bn = blockIdx.x / nbm;              // 0..3
  const int m_base = bm*128, n_base = bn*64;
  const int w = t >> 6, lane = t & 63;
  const int wr = (w >> 1)*64, wc = (w & 1)*32;
  const int fr = lane & 15, fk = lane >> 4;
  const int arow = t >> 1, acol = (t & 1)*16;
  const int brow = t >> 2, bcol = (t & 3)*8;

  v4f acc[4][2];
#pragma unroll
  for (int i = 0; i < 4; i++)
#pragma unroll
    for (int j = 0; j < 2; j++) acc[i][j] = (v4f){0.f,0.f,0.f,0.f};

  for (int k0 = 0; k0 < 256; k0 += 32) {
    __syncthreads();
    {
      int gm = m_base + arow;
      uint4 a0 = make_uint4(0u,0u,0u,0u), a1 = make_uint4(0u,0u,0u,0u);
      if (gm < N) {
        a0 = loadpack8(x + (size_t)gm*256 + k0 + acol);
        a1 = loadpack8(x + (size_t)gm*256 + k0 + acol + 8);
      }
      *(uint4*)&As[arow*40 + acol]     = a0;
      *(uint4*)&As[arow*40 + acol + 8] = a1;
      uint4 bv = loadpack8(wpre + (size_t)(n_base + brow)*256 + k0 + bcol);
      *(uint4*)&Bs[brow*40 + bcol] = bv;
    }
    __syncthreads();
    v8s b0 = *(const v8s*)&Bs[(wc      + fr)*40 + fk*8];
    v8s b1 = *(const v8s*)&Bs[(wc + 16 + fr)*40 + fk*8];
#pragma unroll
    for (int mi = 0; mi < 4; mi++) {
      v8s a = *(const v8s*)&As[(wr + mi*16 + fr)*40 + fk*8];
      acc[mi][0] = __builtin_amdgcn_mfma_f32_16x16x32_bf16(a,b0,acc[mi][0],0,0,0);
      acc[mi][1] = __builtin_amdgcn_mfma_f32_16x16x32_bf16(a,b1,acc[mi][1],0,0,0);
    }
  }

  // ---- epilogue: GroupNorm in-register, yn -> ynL ----
#pragma unroll
  for (int nj = 0; nj < 2; nj++) {
    int col = n_base + wc + nj*16 + fr;
    float bpv = bpre[col];
    int gloc = (w & 1)*2 + nj;                  // group within tile 0..3
#pragma unroll
    for (int mi = 0; mi < 4; mi++) {
#pragma unroll
      for (int r = 0; r < 4; r++) {
        float yv = acc[mi][nj][r] + bpv;
        float s1 = rsum16(yv);
        float s2 = rsum16(yv*yv);
        float mu = s1 * 0.0625f;
        float var = fmaxf(s2*0.0625f - mu*mu, 0.f);
        float ynv = (yv - mu) * rsqrtf(var + GN_EPS);
        int row = wr + mi*16 + fk*4 + r;        // 0..127
        ynL[row*74 + gloc*16 + fr] = f2bf(ynv);
      }
    }
  }
  __syncthreads();   // MFMA LDS reads done; ynL published

  // ---- stage qkv weights for this tile's 4 groups (over As/Bs) ----
  {
    const float* srcs[3] = {wq, wk, wv};
#pragma unroll
    for (int tz = 0; tz < 3; tz++) {
      for (int i = t; i < 2048; i += 256) {
        int gi = i >> 9, rem = i & 511;
        wL[tz*2080 + gi*520 + rem] = srcs[tz][((size_t)(bn*4 + gi))*512 + rem];
      }
    }
  }
  __syncthreads();

  // ---- conv phase: wave w = group w (wave-uniform weights) ----
  u16* outs[3] = {qo, ko, vo};
  const int gl = w;                             // 4 waves, 4 groups
  const int g  = bn*4 + gl;
#pragma unroll
  for (int p = 0; p < 2; p++) {
    int nloc = p*64 + lane;
    int node = m_base + nloc;
    if (node >= N) continue;
    u32 yw[8];
#pragma unroll
    for (int j = 0; j < 8; j++)
      yw[j] = *(const u32*)&ynL[nloc*74 + gl*16 + j*2];
    float yn[16];
#pragma unroll
    for (int j = 0; j < 8; j++) { yn[2*j] = bflo(yw[j]); yn[2*j+1] = bfhi(yw[j]); }
#pragma unroll
    for (int tz = 0; tz < 3; tz++) {
#pragma unroll
      for (int s = 0; s < 2; s++) {
        u32 pk[8];
#pragma unroll
        for (int o = 0; o < 16; o++) {
          float d = dot16(yn, &wL[tz*2080 + gl*520 + (s*16 + o)*16]);
          if (tz < 2) d = __expf(d*0.25f);
          if (o & 1) pk[o>>1] |= (u32)f2bf(d) << 16;
          else       pk[o>>1]  = (u32)f2bf(d);
        }
        u16* dst = outs[tz] + (size_t)node*512 + g*32 + s*16;
        *(uint4*)dst       = make_uint4(pk[0],pk[1],pk[2],pk[3]);
        *(uint4*)(dst + 8) = make_uint4(pk[4],pk[5],pk[6],pk[7]);
      }
    }
  }
}

// =====================================================================
// K3 (512 threads, fused, reduction-free): thread (nh, d) owns output
// row KV[nh][d][0:16] and k_sum[nh][d]; accumulates over ALL graph
// nodes. Phase 2: out1 = KV + xres; kv -> LDS bf16. Phase 3: att.
// =====================================================================
__global__ __launch_bounds__(512) void k_segatt(
    const u16* __restrict__ xk, const u16* __restrict__ xv,
    const u16* __restrict__ xq, const float* __restrict__ xres,
    const int* __restrict__ bounds,
    float* __restrict__ out1, u16* __restrict__ att, int N)
{
  __shared__ __align__(16) u16 kvs[32*280];     // 17.5 KB
  __shared__ float kss[32*17];                  // 2.2 KB
  const int b = blockIdx.x, t = threadIdx.x;
  const int lo = bounds[b], hi = bounds[b+1];
  const int nh = t >> 4, d = t & 15;

  float kv[16];
#pragma unroll
  for (int v = 0; v < 16; v++) kv[v] = 0.f;
  float ks = 0.f;

  const size_t koff = (size_t)nh*16 + d;
  const size_t voff = (size_t)nh*16;
  int node = lo;
  for (; node + 1 < hi; node += 2) {
    u16  ka  = xk[(size_t)node*512 + koff];
    uint4 Va0 = *(const uint4*)(xv + (size_t)node*512 + voff);
    uint4 Va1 = *(const uint4*)(xv + (size_t)node*512 + voff + 8);
    u16  kb  = xk[(size_t)(node+1)*512 + koff];
    uint4 Vb0 = *(const uint4*)(xv + (size_t)(node+1)*512 + voff);
    uint4 Vb1 = *(const uint4*)(xv + (size_t)(node+1)*512 + voff + 8);
    float k0 = bf1(ka), k1 = bf1(kb);
    float va[16], vb[16];
    unpack8(Va0, va); unpack8(Va1, va + 8);
    unpack8(Vb0, vb); unpack8(Vb1, vb + 8);
    ks += k0 + k1;
#pragma unroll
    for (int v = 0; v < 16; v++) {
      kv[v] = fmaf(k0, va[v], kv[v]);
      kv[v] = fmaf(k1, vb[v], kv[v]);
    }
  }
  if (node < hi) {
    u16  ka  = xk[(size_t)node*512 + koff];
    uint4 V0 = *(const uint4*)(xv + (size_t)node*512 + voff);
    uint4 V1 = *(const uint4*)(xv + (size_t)node*512 + voff + 8);
    float k0 = bf1(ka);
    float vf[16]; unpack8(V0, vf); unpack8(V1, vf + 8);
    ks += k0;
#pragma unroll
    for (int v = 0; v < 16; v++) kv[v] = fmaf(k0, vf[v], kv[v]);
  }

  kss[nh*17 + d] = ks;

  {
    size_t idx = ((size_t)(b*32 + nh)*16 + d)*16;
    const float* xp = xres + idx;
    float4 X0 = *(const float4*)xp;
    float4 X1 = *(const float4*)(xp + 4);
    float4 X2 = *(const float4*)(xp + 8);
    float4 X3 = *(const float4*)(xp + 12);
    float xf[16] = {X0.x,X0.y,X0.z,X0.w,X1.x,X1.y,X1.z,X1.w,
                    X2.x,X2.y,X2.z,X2.w,X3.x,X3.y,X3.z,X3.w};
    float o[16];
#pragma unroll
    for (int j = 0; j < 16; j++) o[j] = kv[j] + xf[j];
    float* op = out1 + idx;
    *(float4*)op        = make_float4(o[0],o[1],o[2],o[3]);
    *(float4*)(op + 4)  = make_float4(o[4],o[5],o[6],o[7]);
    *(float4*)(op + 8)  = make_float4(o[8],o[9],o[10],o[11]);
    *(float4*)(op + 12) = make_float4(o[12],o[13],o[14],o[15]);
    u16* lp = &kvs[nh*280 + d*16];
    *(uint4*)lp       = make_uint4(pack2(o[0],o[1]),  pack2(o[2],o[3]),
                                   pack2(o[4],o[5]),  pack2(o[6],o[7]));
    *(uint4*)(lp + 8) = make_uint4(pack2(o[8],o[9]),  pack2(o[10],o[11]),
                                   pack2(o[12],o[13]),pack2(o[14],o[15]));
  }
  __syncthreads();

  const int nh2 = t & 31, ns = t >> 5;   // ns 0..15
  for (int n0 = lo; n0 < hi; n0 += 16) {
    int nodei = n0 + ns;
    if (nodei >= hi) continue;
    const u16* qp = xq + (size_t)nodei*512 + nh2*16;
    uint4 Q0 = *(const uint4*)qp;
    uint4 Q1 = *(const uint4*)(qp + 8);
    float q[16]; unpack8(Q0, q); unpack8(Q1, q + 8);
    const float* ksp = &kss[nh2*17];
    float denom = 0.f;
#pragma unroll
    for (int i = 0; i < 16; i++) denom = fmaf(q[i], ksp[i], denom);
    float inv = 1.0f / fmaxf(denom, 1e-20f);
    float a[16];
#pragma unroll
    for (int v = 0; v < 16; v++) a[v] = 0.f;
    const u16* kvp = &kvs[nh2*280];
#pragma unroll
    for (int h = 0; h < 16; h++) {
      float qh = q[h] * inv;
      uint4 W0 = *(const uint4*)(kvp + h*16);
      uint4 W1 = *(const uint4*)(kvp + h*16 + 8);
      float wv2[16]; unpack8(W0, wv2); unpack8(W1, wv2 + 8);
#pragma unroll
      for (int v = 0; v < 16; v++) a[v] = fmaf(qh, wv2[v], a[v]);
    }
    u32 p[8];
#pragma unroll
    for (int j = 0; j < 8; j++) p[j] = pack2(a[2*j], a[2*j+1]);
    u16* dst = att + (size_t)nodei*512 + nh2*16;
    *(uint4*)dst       = make_uint4(p[0],p[1],p[2],p[3]);
    *(uint4*)(dst + 8) = make_uint4(p[4],p[5],p[6],p[7]);
  }
}

// =====================================================================
// K5 (MFMA): out0 = exp(log_scale) * (att @ w_post^T + b_post), K=512.
// Tile 128x64.
// =====================================================================
__global__ __launch_bounds__(256) void k_post(
    const u16* __restrict__ att, const float* __restrict__ wpost,
    const float* __restrict__ bpost, const float* __restrict__ ls,
    float* __restrict__ out0, int N, int nbm)
{
  __shared__ __align__(16) u16 As[128*40];
  __shared__ __align__(16) u16 Bs[64*40];
  const int t = threadIdx.x;
  const int bm = blockIdx.x % nbm;
  const int bn = blockIdx.x / nbm;          // 0..3
  const int m_base = bm*128, n_base = bn*64;
  const int w = t >> 6, lane = t & 63;
  const int wr = (w >> 1)*64, wc = (w & 1)*32;
  const int fr = lane & 15, fk = lane >> 4;
  const int arow = t >> 1, acol = (t & 1)*16;
  const int brow = t >> 2, bcol = (t & 3)*8;

  v4f acc[4][2];
#pragma unroll
  for (int i = 0; i < 4; i++)
#pragma unroll
    for (int j = 0; j < 2; j++) acc[i][j] = (v4f){0.f,0.f,0.f,0.f};

  for (int k0 = 0; k0 < 512; k0 += 32) {
    __syncthreads();
    {
      int gm = m_base + arow;
      uint4 a0 = make_uint4(0u,0u,0u,0u), a1 = make_uint4(0u,0u,0u,0u);
      if (gm < N) {
        a0 = *(const uint4*)(att + (size_t)gm*512 + k0 + acol);
        a1 = *(const uint4*)(att + (size_t)gm*512 + k0 + acol + 8);
      }
      *(uint4*)&As[arow*40 + acol]     = a0;
      *(uint4*)&As[arow*40 + acol + 8] = a1;
      uint4 bv = loadpack8(wpost + (size_t)(n_base + brow)*512 + k0 + bcol);
      *(uint4*)&Bs[brow*40 + bcol] = bv;
    }
    __syncthreads();
    v8s b0 = *(const v8s*)&Bs[(wc      + fr)*40 + fk*8];
    v8s b1 = *(const v8s*)&Bs[(wc + 16 + fr)*40 + fk*8];
#pragma unroll
    for (int mi = 0; mi < 4; mi++) {
      v8s a = *(const v8s*)&As[(wr + mi*16 + fr)*40 + fk*8];
      acc[mi][0] = __builtin_amdgcn_mfma_f32_16x16x32_bf16(a,b0,acc[mi][0],0,0,0);
      acc[mi][1] = __builtin_amdgcn_mfma_f32_16x16x32_bf16(a,b1,acc[mi][1],0,0,0);
    }
  }
#pragma unroll
  for (int nj = 0; nj < 2; nj++) {
    int col = n_base + wc + nj*16 + fr;
    float bpv = bpost[col];
    float e   = __expf(ls[col]);
#pragma unroll
    for (int mi = 0; mi < 4; mi++) {
#pragma unroll
      for (int r = 0; r < 4; r++) {
        int row = m_base + wr + mi*16 + fk*4 + r;
        if (row < N) out0[(size_t)row*256 + col] = e*(acc[mi][nj][r] + bpv);
      }
    }
  }
}

// =====================================================================
extern "C" void kernel_launch(void* const* d_in, const int* in_sizes, int n_in,
                              void* d_out, int out_size, void* d_ws, size_t ws_size,
                              hipStream_t stream)
{
  const float* x     = (const float*)d_in[0];
  const float* xres  = (const float*)d_in[1];
  const int*   batch = (const int*)d_in[2];
  const float* wpre  = (const float*)d_in[4];
  const float* bpre  = (const float*)d_in[5];
  const float* wq    = (const float*)d_in[6];
  const float* wk    = (const float*)d_in[7];
  const float* wv    = (const float*)d_in[8];
  const float* wpost = (const float*)d_in[9];
  const float* bpost = (const float*)d_in[10];
  const float* ls    = (const float*)d_in[11];

  const int N = in_sizes[0] / 256;     // 20000 nodes
  const int B = in_sizes[1] / 8192;    // 1024 graphs
  const int nbm = (N + 127) / 128;     // 157 row tiles
  const int nchunk = (N + 255) / 256;  // 79 node chunks

  char* ws = (char*)d_ws;
  size_t off = 0;
  int*   flags  = (int*)(ws + off); off += 256;
  int*   bounds = (int*)(ws + off); off += ((size_t)B + 64) * 4;
  u16*   att    = (u16*)(ws + off);  off += (size_t)N * 1024;
  u16*   q      = (u16*)(ws + off);  off += (size_t)N * 1024;
  u16*   kten   = (u16*)(ws + off);  off += (size_t)N * 1024;
  u16*   vten   = (u16*)(ws + off);  off += (size_t)N * 1024;

  float* out0 = (float*)d_out;
  float* out1 = out0 + (size_t)N * 256;

  hipMemsetAsync(flags, 0, 4, stream);
  k_detect  <<<nchunk,        256, 0, stream>>>(batch, N, flags);
  k_bounds  <<<nchunk,        256, 0, stream>>>(batch, flags, N, B, bounds);
  k_prefused<<<nbm * 4,       256, 0, stream>>>(x, wpre, bpre, wq, wk, wv,
                                                q, kten, vten, N, nbm);
  k_segatt  <<<B,             512, 0, stream>>>(kten, vten, q, xres, bounds,
                                                out1, att, N);
  k_post    <<<nbm * 4,       256, 0, stream>>>(att, wpost, bpost, ls, out0, N, nbm);
}

// Round 22
// 121.272 us; speedup vs baseline: 1.4681x; 1.0587x over previous
//
#include <hip/hip_runtime.h>
#include <stdint.h>

typedef unsigned int u32;
typedef unsigned short u16;
typedef __attribute__((ext_vector_type(8))) short v8s;   // 8 bf16 (4 VGPRs)
typedef __attribute__((ext_vector_type(4))) float v4f;   // 4 f32 acc

#define GN_EPS 1e-5f

// ---------- bf16 helpers (intermediates in ws are bf16) ----------
__device__ __forceinline__ float bflo(u32 u){ return __uint_as_float(u << 16); }
__device__ __forceinline__ float bfhi(u32 u){ return __uint_as_float(u & 0xffff0000u); }
__device__ __forceinline__ float bf1(u16 u){ return __uint_as_float((u32)u << 16); }
__device__ __forceinline__ u16 f2bf(float f){
  u32 x = __float_as_uint(f);
  u32 r = (x + 0x7fffu + ((x >> 16) & 1u)) >> 16;   // RNE
  return (u16)r;
}
__device__ __forceinline__ u32 pack2(float a, float b){
  return (u32)f2bf(a) | ((u32)f2bf(b) << 16);
}
__device__ __forceinline__ void unpack8(const uint4 u, float* f){
  f[0]=bflo(u.x); f[1]=bfhi(u.x); f[2]=bflo(u.y); f[3]=bfhi(u.y);
  f[4]=bflo(u.z); f[5]=bfhi(u.z); f[6]=bflo(u.w); f[7]=bfhi(u.w);
}
// load 8 f32, return packed bf16 (4 u32)
__device__ __forceinline__ uint4 loadpack8(const float* __restrict__ p){
  float4 a = *(const float4*)p, b = *(const float4*)(p + 4);
  return make_uint4(pack2(a.x,a.y),pack2(a.z,a.w),pack2(b.x,b.y),pack2(b.z,b.w));
}
__device__ __forceinline__ float dot16(const float* __restrict__ yn,
                                       const float* __restrict__ row){
  float4 W0 = *(const float4*)row;
  float4 W1 = *(const float4*)(row + 4);
  float4 W2 = *(const float4*)(row + 8);
  float4 W3 = *(const float4*)(row + 12);
  float d = 0.f;
  d = fmaf(yn[0],W0.x,d); d = fmaf(yn[1],W0.y,d);
  d = fmaf(yn[2],W0.z,d); d = fmaf(yn[3],W0.w,d);
  d = fmaf(yn[4],W1.x,d); d = fmaf(yn[5],W1.y,d);
  d = fmaf(yn[6],W1.z,d); d = fmaf(yn[7],W1.w,d);
  d = fmaf(yn[8],W2.x,d); d = fmaf(yn[9],W2.y,d);
  d = fmaf(yn[10],W2.z,d); d = fmaf(yn[11],W2.w,d);
  d = fmaf(yn[12],W3.x,d); d = fmaf(yn[13],W3.y,d);
  d = fmaf(yn[14],W3.z,d); d = fmaf(yn[15],W3.w,d);
  return d;
}
__device__ __forceinline__ float rsum16(float v){
  v += __shfl_xor(v, 1);
  v += __shfl_xor(v, 2);
  v += __shfl_xor(v, 4);
  v += __shfl_xor(v, 8);
  return v;
}
// bijective XCD-chunked block remap (m204 variant): consecutive logical
// blocks land on the SAME XCD so same-row col-blocks share L2.
__device__ __forceinline__ int xcd_remap(int bid, int grid){
  int xcd = bid & 7;
  int q8 = grid >> 3, r8 = grid & 7;
  int base = (xcd < r8) ? xcd*(q8+1) : r8*(q8+1) + (xcd - r8)*q8;
  return base + (bid >> 3);
}

// batch accessor: int32 or int64 (little-endian low word)
__device__ __forceinline__ int getb(const int* __restrict__ b, int is64, int i){
  return b[is64 ? 2*i : i];
}

// =====================================================================
// K0: detect batch int-width (parallel).
// =====================================================================
__global__ __launch_bounds__(256) void k_detect(
    const int* __restrict__ batch, int n, int* __restrict__ flags)
{
  int i = blockIdx.x*256 + threadIdx.x;
  int bad = 0;
  if (i < n - 1 && batch[i] > batch[i + 1]) bad = 1;
  if (__builtin_amdgcn_ballot_w64(bad) != 0 && (threadIdx.x & 63) == 0)
    atomicOr(&flags[0], 1);
}

// =====================================================================
// K0b: CSR bounds. bounds[g] = first node of graph g; bounds[B] = N.
// =====================================================================
__global__ __launch_bounds__(256) void k_bounds(
    const int* __restrict__ batch, const int* __restrict__ flags,
    int N, int B, int* __restrict__ bounds)
{
  int i = blockIdx.x*256 + threadIdx.x;
  if (i >= N) return;
  const int is64 = flags[0];
  int b = getb(batch, is64, i);
  int prev = (i == 0) ? -1 : getb(batch, is64, i - 1);
  for (int g = prev + 1; g <= b; g++) bounds[g] = i;
  if (i == N - 1)
    for (int g = b + 1; g <= B; g++) bounds[g] = N;
}

// =====================================================================
// K1 (fused MFMA GEMM + GroupNorm + grouped QKV convs).
// Tile 128 nodes x 64 cols (= 4 complete groups). XCD-swizzled block
// order: the 4 col-blocks of one row-tile are consecutive on one XCD.
// =====================================================================
__global__ __launch_bounds__(256) void k_prefused(
    const float* __restrict__ x, const float* __restrict__ wpre,
    const float* __restrict__ bpre,
    const float* __restrict__ wq, const float* __restrict__ wk,
    const float* __restrict__ wv,
    u16* __restrict__ qo, u16* __restrict__ ko, u16* __restrict__ vo,
    int N, int nbm)
{
  __shared__ __align__(16) char SMEM[25600];    // As/Bs (15.3K) then wL (25K)
  __shared__ __align__(16) u16 ynL[128*74];     // 18.5 KB
  u16* As = (u16*)SMEM;                         // 128*40
  u16* Bs = (u16*)(SMEM + 128*40*2);            // 64*40
  float* wL = (float*)SMEM;                     // 3*2080 f32 after barrier

  const int t = threadIdx.x;
  const int l  = xcd_remap(blockIdx.x, nbm*4);
  const int bm = l >> 2;
  const int bn = l & 3;
  const int m_base = bm*128, n_base = bn*64;
  const int w = t >> 6, lane = t & 63;
  const int wr = (w >> 1)*64, wc = (w & 1)*32;
  const int fr = lane & 15, fk = lane >> 4;
  const int arow = t >> 1, acol = (t & 1)*16;
  const int brow = t >> 2, bcol = (t & 3)*8;

  v4f acc[4][2];
#pragma unroll
  for (int i = 0; i < 4; i++)
#pragma unroll
    for (int j = 0; j < 2; j++) acc[i][j] = (v4f){0.f,0.f,0.f,0.f};

  for (int k0 = 0; k0 < 256; k0 += 32) {
    __syncthreads();
    {
      int gm = m_base + arow;
      uint4 a0 = make_uint4(0u,0u,0u,0u), a1 = make_uint4(0u,0u,0u,0u);
      if (gm < N) {
        a0 = loadpack8(x + (size_t)gm*256 + k0 + acol);
        a1 = loadpack8(x + (size_t)gm*256 + k0 + acol + 8);
      }
      *(uint4*)&As[arow*40 + acol]     = a0;
      *(uint4*)&As[arow*40 + acol + 8] = a1;
      uint4 bv = loadpack8(wpre + (size_t)(n_base + brow)*256 + k0 + bcol);
      *(uint4*)&Bs[brow*40 + bcol] = bv;
    }
    __syncthreads();
    v8s b0 = *(const v8s*)&Bs[(wc      + fr)*40 + fk*8];
    v8s b1 = *(const v8s*)&Bs[(wc + 16 + fr)*40 + fk*8];
#pragma unroll
    for (int mi = 0; mi < 4; mi++) {
      v8s a = *(const v8s*)&As[(wr + mi*16 + fr)*40 + fk*8];
      acc[mi][0] = __builtin_amdgcn_mfma_f32_16x16x32_bf16(a,b0,acc[mi][0],0,0,0);
      acc[mi][1] = __builtin_amdgcn_mfma_f32_16x16x32_bf16(a,b1,acc[mi][1],0,0,0);
    }
  }

  // ---- epilogue: GroupNorm in-register, yn -> ynL ----
#pragma unroll
  for (int nj = 0; nj < 2; nj++) {
    int col = n_base + wc + nj*16 + fr;
    float bpv = bpre[col];
    int gloc = (w & 1)*2 + nj;                  // group within tile 0..3
#pragma unroll
    for (int mi = 0; mi < 4; mi++) {
#pragma unroll
      for (int r = 0; r < 4; r++) {
        float yv = acc[mi][nj][r] + bpv;
        float s1 = rsum16(yv);
        float s2 = rsum16(yv*yv);
        float mu = s1 * 0.0625f;
        float var = fmaxf(s2*0.0625f - mu*mu, 0.f);
        float ynv = (yv - mu) * rsqrtf(var + GN_EPS);
        int row = wr + mi*16 + fk*4 + r;        // 0..127
        ynL[row*74 + gloc*16 + fr] = f2bf(ynv);
      }
    }
  }
  __syncthreads();   // MFMA LDS reads done; ynL published

  // ---- stage qkv weights for this tile's 4 groups (over As/Bs) ----
  {
    const float* srcs[3] = {wq, wk, wv};
#pragma unroll
    for (int tz = 0; tz < 3; tz++) {
      for (int i = t; i < 2048; i += 256) {
        int gi = i >> 9, rem = i & 511;
        wL[tz*2080 + gi*520 + rem] = srcs[tz][((size_t)(bn*4 + gi))*512 + rem];
      }
    }
  }
  __syncthreads();

  // ---- conv phase: wave w = group w (wave-uniform weights) ----
  u16* outs[3] = {qo, ko, vo};
  const int gl = w;                             // 4 waves, 4 groups
  const int g  = bn*4 + gl;
#pragma unroll
  for (int p = 0; p < 2; p++) {
    int nloc = p*64 + lane;
    int node = m_base + nloc;
    if (node >= N) continue;
    u32 yw[8];
#pragma unroll
    for (int j = 0; j < 8; j++)
      yw[j] = *(const u32*)&ynL[nloc*74 + gl*16 + j*2];
    float yn[16];
#pragma unroll
    for (int j = 0; j < 8; j++) { yn[2*j] = bflo(yw[j]); yn[2*j+1] = bfhi(yw[j]); }
#pragma unroll
    for (int tz = 0; tz < 3; tz++) {
#pragma unroll
      for (int s = 0; s < 2; s++) {
        u32 pk[8];
#pragma unroll
        for (int o = 0; o < 16; o++) {
          float d = dot16(yn, &wL[tz*2080 + gl*520 + (s*16 + o)*16]);
          if (tz < 2) d = __expf(d*0.25f);
          if (o & 1) pk[o>>1] |= (u32)f2bf(d) << 16;
          else       pk[o>>1]  = (u32)f2bf(d);
        }
        u16* dst = outs[tz] + (size_t)node*512 + g*32 + s*16;
        *(uint4*)dst       = make_uint4(pk[0],pk[1],pk[2],pk[3]);
        *(uint4*)(dst + 8) = make_uint4(pk[4],pk[5],pk[6],pk[7]);
      }
    }
  }
}

// =====================================================================
// K3 (512 threads, fused, reduction-free): thread (nh, d) owns output
// row KV[nh][d][0:16] and k_sum[nh][d]; accumulates over ALL graph
// nodes. Phase 2: out1 = KV + xres; kv -> LDS bf16. Phase 3: att.
// =====================================================================
__global__ __launch_bounds__(512) void k_segatt(
    const u16* __restrict__ xk, const u16* __restrict__ xv,
    const u16* __restrict__ xq, const float* __restrict__ xres,
    const int* __restrict__ bounds,
    float* __restrict__ out1, u16* __restrict__ att, int N)
{
  __shared__ __align__(16) u16 kvs[32*280];     // 17.5 KB
  __shared__ float kss[32*17];                  // 2.2 KB
  const int b = blockIdx.x, t = threadIdx.x;
  const int lo = bounds[b], hi = bounds[b+1];
  const int nh = t >> 4, d = t & 15;

  float kv[16];
#pragma unroll
  for (int v = 0; v < 16; v++) kv[v] = 0.f;
  float ks = 0.f;

  const size_t koff = (size_t)nh*16 + d;
  const size_t voff = (size_t)nh*16;
  int node = lo;
  for (; node + 1 < hi; node += 2) {
    u16  ka  = xk[(size_t)node*512 + koff];
    uint4 Va0 = *(const uint4*)(xv + (size_t)node*512 + voff);
    uint4 Va1 = *(const uint4*)(xv + (size_t)node*512 + voff + 8);
    u16  kb  = xk[(size_t)(node+1)*512 + koff];
    uint4 Vb0 = *(const uint4*)(xv + (size_t)(node+1)*512 + voff);
    uint4 Vb1 = *(const uint4*)(xv + (size_t)(node+1)*512 + voff + 8);
    float k0 = bf1(ka), k1 = bf1(kb);
    float va[16], vb[16];
    unpack8(Va0, va); unpack8(Va1, va + 8);
    unpack8(Vb0, vb); unpack8(Vb1, vb + 8);
    ks += k0 + k1;
#pragma unroll
    for (int v = 0; v < 16; v++) {
      kv[v] = fmaf(k0, va[v], kv[v]);
      kv[v] = fmaf(k1, vb[v], kv[v]);
    }
  }
  if (node < hi) {
    u16  ka  = xk[(size_t)node*512 + koff];
    uint4 V0 = *(const uint4*)(xv + (size_t)node*512 + voff);
    uint4 V1 = *(const uint4*)(xv + (size_t)node*512 + voff + 8);
    float k0 = bf1(ka);
    float vf[16]; unpack8(V0, vf); unpack8(V1, vf + 8);
    ks += k0;
#pragma unroll
    for (int v = 0; v < 16; v++) kv[v] = fmaf(k0, vf[v], kv[v]);
  }

  kss[nh*17 + d] = ks;

  {
    size_t idx = ((size_t)(b*32 + nh)*16 + d)*16;
    const float* xp = xres + idx;
    float4 X0 = *(const float4*)xp;
    float4 X1 = *(const float4*)(xp + 4);
    float4 X2 = *(const float4*)(xp + 8);
    float4 X3 = *(const float4*)(xp + 12);
    float xf[16] = {X0.x,X0.y,X0.z,X0.w,X1.x,X1.y,X1.z,X1.w,
                    X2.x,X2.y,X2.z,X2.w,X3.x,X3.y,X3.z,X3.w};
    float o[16];
#pragma unroll
    for (int j = 0; j < 16; j++) o[j] = kv[j] + xf[j];
    float* op = out1 + idx;
    *(float4*)op        = make_float4(o[0],o[1],o[2],o[3]);
    *(float4*)(op + 4)  = make_float4(o[4],o[5],o[6],o[7]);
    *(float4*)(op + 8)  = make_float4(o[8],o[9],o[10],o[11]);
    *(float4*)(op + 12) = make_float4(o[12],o[13],o[14],o[15]);
    u16* lp = &kvs[nh*280 + d*16];
    *(uint4*)lp       = make_uint4(pack2(o[0],o[1]),  pack2(o[2],o[3]),
                                   pack2(o[4],o[5]),  pack2(o[6],o[7]));
    *(uint4*)(lp + 8) = make_uint4(pack2(o[8],o[9]),  pack2(o[10],o[11]),
                                   pack2(o[12],o[13]),pack2(o[14],o[15]));
  }
  __syncthreads();

  const int nh2 = t & 31, ns = t >> 5;   // ns 0..15
  for (int n0 = lo; n0 < hi; n0 += 16) {
    int nodei = n0 + ns;
    if (nodei >= hi) continue;
    const u16* qp = xq + (size_t)nodei*512 + nh2*16;
    uint4 Q0 = *(const uint4*)qp;
    uint4 Q1 = *(const uint4*)(qp + 8);
    float q[16]; unpack8(Q0, q); unpack8(Q1, q + 8);
    const float* ksp = &kss[nh2*17];
    float denom = 0.f;
#pragma unroll
    for (int i = 0; i < 16; i++) denom = fmaf(q[i], ksp[i], denom);
    float inv = 1.0f / fmaxf(denom, 1e-20f);
    float a[16];
#pragma unroll
    for (int v = 0; v < 16; v++) a[v] = 0.f;
    const u16* kvp = &kvs[nh2*280];
#pragma unroll
    for (int h = 0; h < 16; h++) {
      float qh = q[h] * inv;
      uint4 W0 = *(const uint4*)(kvp + h*16);
      uint4 W1 = *(const uint4*)(kvp + h*16 + 8);
      float wv2[16]; unpack8(W0, wv2); unpack8(W1, wv2 + 8);
#pragma unroll
      for (int v = 0; v < 16; v++) a[v] = fmaf(qh, wv2[v], a[v]);
    }
    u32 p[8];
#pragma unroll
    for (int j = 0; j < 8; j++) p[j] = pack2(a[2*j], a[2*j+1]);
    u16* dst = att + (size_t)nodei*512 + nh2*16;
    *(uint4*)dst       = make_uint4(p[0],p[1],p[2],p[3]);
    *(uint4*)(dst + 8) = make_uint4(p[4],p[5],p[6],p[7]);
  }
}

// =====================================================================
// K5 (MFMA): out0 = exp(log_scale) * (att @ w_post^T + b_post), K=512.
// Tile 128x64, XCD-swizzled block order (att-row L2 sharing).
// =====================================================================
__global__ __launch_bounds__(256) void k_post(
    const u16* __restrict__ att, const float* __restrict__ wpost,
    const float* __restrict__ bpost, const float* __restrict__ ls,
    float* __restrict__ out0, int N, int nbm)
{
  __shared__ __align__(16) u16 As[128*40];
  __shared__ __align__(16) u16 Bs[64*40];
  const int t = threadIdx.x;
  const int l  = xcd_remap(blockIdx.x, nbm*4);
  const int bm = l >> 2;
  const int bn = l & 3;
  const int m_base = bm*128, n_base = bn*64;
  const int w = t >> 6, lane = t & 63;
  const int wr = (w >> 1)*64, wc = (w & 1)*32;
  const int fr = lane & 15, fk = lane >> 4;
  const int arow = t >> 1, acol = (t & 1)*16;
  const int brow = t >> 2, bcol = (t & 3)*8;

  v4f acc[4][2];
#pragma unroll
  for (int i = 0; i < 4; i++)
#pragma unroll
    for (int j = 0; j < 2; j++) acc[i][j] = (v4f){0.f,0.f,0.f,0.f};

  for (int k0 = 0; k0 < 512; k0 += 32) {
    __syncthreads();
    {
      int gm = m_base + arow;
      uint4 a0 = make_uint4(0u,0u,0u,0u), a1 = make_uint4(0u,0u,0u,0u);
      if (gm < N) {
        a0 = *(const uint4*)(att + (size_t)gm*512 + k0 + acol);
        a1 = *(const uint4*)(att + (size_t)gm*512 + k0 + acol + 8);
      }
      *(uint4*)&As[arow*40 + acol]     = a0;
      *(uint4*)&As[arow*40 + acol + 8] = a1;
      uint4 bv = loadpack8(wpost + (size_t)(n_base + brow)*512 + k0 + bcol);
      *(uint4*)&Bs[brow*40 + bcol] = bv;
    }
    __syncthreads();
    v8s b0 = *(const v8s*)&Bs[(wc      + fr)*40 + fk*8];
    v8s b1 = *(const v8s*)&Bs[(wc + 16 + fr)*40 + fk*8];
#pragma unroll
    for (int mi = 0; mi < 4; mi++) {
      v8s a = *(const v8s*)&As[(wr + mi*16 + fr)*40 + fk*8];
      acc[mi][0] = __builtin_amdgcn_mfma_f32_16x16x32_bf16(a,b0,acc[mi][0],0,0,0);
      acc[mi][1] = __builtin_amdgcn_mfma_f32_16x16x32_bf16(a,b1,acc[mi][1],0,0,0);
    }
  }
#pragma unroll
  for (int nj = 0; nj < 2; nj++) {
    int col = n_base + wc + nj*16 + fr;
    float bpv = bpost[col];
    float e   = __expf(ls[col]);
#pragma unroll
    for (int mi = 0; mi < 4; mi++) {
#pragma unroll
      for (int r = 0; r < 4; r++) {
        int row = m_base + wr + mi*16 + fk*4 + r;
        if (row < N) out0[(size_t)row*256 + col] = e*(acc[mi][nj][r] + bpv);
      }
    }
  }
}

// =====================================================================
extern "C" void kernel_launch(void* const* d_in, const int* in_sizes, int n_in,
                              void* d_out, int out_size, void* d_ws, size_t ws_size,
                              hipStream_t stream)
{
  const float* x     = (const float*)d_in[0];
  const float* xres  = (const float*)d_in[1];
  const int*   batch = (const int*)d_in[2];
  const float* wpre  = (const float*)d_in[4];
  const float* bpre  = (const float*)d_in[5];
  const float* wq    = (const float*)d_in[6];
  const float* wk    = (const float*)d_in[7];
  const float* wv    = (const float*)d_in[8];
  const float* wpost = (const float*)d_in[9];
  const float* bpost = (const float*)d_in[10];
  const float* ls    = (const float*)d_in[11];

  const int N = in_sizes[0] / 256;     // 20000 nodes
  const int B = in_sizes[1] / 8192;    // 1024 graphs
  const int nbm = (N + 127) / 128;     // 157 row tiles
  const int nchunk = (N + 255) / 256;  // 79 node chunks

  char* ws = (char*)d_ws;
  size_t off = 0;
  int*   flags  = (int*)(ws + off); off += 256;
  int*   bounds = (int*)(ws + off); off += ((size_t)B + 64) * 4;
  u16*   att    = (u16*)(ws + off);  off += (size_t)N * 1024;
  u16*   q      = (u16*)(ws + off);  off += (size_t)N * 1024;
  u16*   kten   = (u16*)(ws + off);  off += (size_t)N * 1024;
  u16*   vten   = (u16*)(ws + off);  off += (size_t)N * 1024;

  float* out0 = (float*)d_out;
  float* out1 = out0 + (size_t)N * 256;

  hipMemsetAsync(flags, 0, 4, stream);
  k_detect  <<<nchunk,        256, 0, stream>>>(batch, N, flags);
  k_bounds  <<<nchunk,        256, 0, stream>>>(batch, flags, N, B, bounds);
  k_prefused<<<nbm * 4,       256, 0, stream>>>(x, wpre, bpre, wq, wk, wv,
                                                q, kten, vten, N, nbm);
  k_segatt  <<<B,             512, 0, stream>>>(kten, vten, q, xres, bounds,
                                                out1, att, N);
  k_post    <<<nbm * 4,       256, 0, stream>>>(att, wpost, bpost, ls, out0, N, nbm);
}

// Round 23
// 120.430 us; speedup vs baseline: 1.4783x; 1.0070x over previous
//
#include <hip/hip_runtime.h>
#include <stdint.h>

typedef unsigned int u32;
typedef unsigned short u16;
typedef __attribute__((ext_vector_type(8))) short v8s;   // 8 bf16 (4 VGPRs)
typedef __attribute__((ext_vector_type(4))) float v4f;   // 4 f32 acc

#define GN_EPS 1e-5f

// ---------- bf16 helpers (intermediates in ws are bf16) ----------
__device__ __forceinline__ float bflo(u32 u){ return __uint_as_float(u << 16); }
__device__ __forceinline__ float bfhi(u32 u){ return __uint_as_float(u & 0xffff0000u); }
__device__ __forceinline__ float bf1(u16 u){ return __uint_as_float((u32)u << 16); }
__device__ __forceinline__ u16 f2bf(float f){
  u32 x = __float_as_uint(f);
  u32 r = (x + 0x7fffu + ((x >> 16) & 1u)) >> 16;   // RNE
  return (u16)r;
}
__device__ __forceinline__ u32 pack2(float a, float b){
  return (u32)f2bf(a) | ((u32)f2bf(b) << 16);
}
__device__ __forceinline__ void unpack8(const uint4 u, float* f){
  f[0]=bflo(u.x); f[1]=bfhi(u.x); f[2]=bflo(u.y); f[3]=bfhi(u.y);
  f[4]=bflo(u.z); f[5]=bfhi(u.z); f[6]=bflo(u.w); f[7]=bfhi(u.w);
}
// load 8 f32, return packed bf16 (4 u32)
__device__ __forceinline__ uint4 loadpack8(const float* __restrict__ p){
  float4 a = *(const float4*)p, b = *(const float4*)(p + 4);
  return make_uint4(pack2(a.x,a.y),pack2(a.z,a.w),pack2(b.x,b.y),pack2(b.z,b.w));
}
__device__ __forceinline__ float dot16(const float* __restrict__ yn,
                                       const float* __restrict__ row){
  float4 W0 = *(const float4*)row;
  float4 W1 = *(const float4*)(row + 4);
  float4 W2 = *(const float4*)(row + 8);
  float4 W3 = *(const float4*)(row + 12);
  float d = 0.f;
  d = fmaf(yn[0],W0.x,d); d = fmaf(yn[1],W0.y,d);
  d = fmaf(yn[2],W0.z,d); d = fmaf(yn[3],W0.w,d);
  d = fmaf(yn[4],W1.x,d); d = fmaf(yn[5],W1.y,d);
  d = fmaf(yn[6],W1.z,d); d = fmaf(yn[7],W1.w,d);
  d = fmaf(yn[8],W2.x,d); d = fmaf(yn[9],W2.y,d);
  d = fmaf(yn[10],W2.z,d); d = fmaf(yn[11],W2.w,d);
  d = fmaf(yn[12],W3.x,d); d = fmaf(yn[13],W3.y,d);
  d = fmaf(yn[14],W3.z,d); d = fmaf(yn[15],W3.w,d);
  return d;
}
__device__ __forceinline__ float rsum16(float v){
  v += __shfl_xor(v, 1);
  v += __shfl_xor(v, 2);
  v += __shfl_xor(v, 4);
  v += __shfl_xor(v, 8);
  return v;
}
// bijective XCD-chunked block remap (m204 variant)
__device__ __forceinline__ int xcd_remap(int bid, int grid){
  int xcd = bid & 7;
  int q8 = grid >> 3, r8 = grid & 7;
  int base = (xcd < r8) ? xcd*(q8+1) : r8*(q8+1) + (xcd - r8)*q8;
  return base + (bid >> 3);
}

// batch accessor: int32 or int64 (little-endian low word)
__device__ __forceinline__ int getb(const int* __restrict__ b, int is64, int i){
  return b[is64 ? 2*i : i];
}

// =====================================================================
// K0: detect batch int-width (parallel).
// =====================================================================
__global__ __launch_bounds__(256) void k_detect(
    const int* __restrict__ batch, int n, int* __restrict__ flags)
{
  int i = blockIdx.x*256 + threadIdx.x;
  int bad = 0;
  if (i < n - 1 && batch[i] > batch[i + 1]) bad = 1;
  if (__builtin_amdgcn_ballot_w64(bad) != 0 && (threadIdx.x & 63) == 0)
    atomicOr(&flags[0], 1);
}

// =====================================================================
// K0b: CSR bounds. bounds[g] = first node of graph g; bounds[B] = N.
// =====================================================================
__global__ __launch_bounds__(256) void k_bounds(
    const int* __restrict__ batch, const int* __restrict__ flags,
    int N, int B, int* __restrict__ bounds)
{
  int i = blockIdx.x*256 + threadIdx.x;
  if (i >= N) return;
  const int is64 = flags[0];
  int b = getb(batch, is64, i);
  int prev = (i == 0) ? -1 : getb(batch, is64, i - 1);
  for (int g = prev + 1; g <= b; g++) bounds[g] = i;
  if (i == N - 1)
    for (int g = b + 1; g <= B; g++) bounds[g] = N;
}

// =====================================================================
// K1 (fused MFMA GEMM + GroupNorm + grouped QKV convs), 64x64 tile.
// Grid 1252 (4.9 blocks/CU); LDS 35.1KB -> 4 blocks/CU. Wave tile
// 32x32 (acc 2x2); conv: wave w = group w, single 64-lane pass.
// XCD-swizzled block order (4 col-blocks of a row-tile share L2).
// =====================================================================
__global__ __launch_bounds__(256) void k_prefused(
    const float* __restrict__ x, const float* __restrict__ wpre,
    const float* __restrict__ bpre,
    const float* __restrict__ wq, const float* __restrict__ wk,
    const float* __restrict__ wv,
    u16* __restrict__ qo, u16* __restrict__ ko, u16* __restrict__ vo,
    int N, int nbm)
{
  __shared__ __align__(16) char SMEM[25600];    // As+Bs (10.2K) / wL (25K)
  __shared__ __align__(16) u16 ynL[64*74];      // 9.3 KB
  u16* As = (u16*)SMEM;                         // 64*40
  u16* Bs = (u16*)(SMEM + 64*40*2);             // 64*40
  float* wL = (float*)SMEM;                     // 3*2080 f32 after barrier

  const int t = threadIdx.x;
  const int l  = xcd_remap(blockIdx.x, nbm*4);
  const int bm = l >> 2;
  const int bn = l & 3;
  const int m_base = bm*64, n_base = bn*64;
  const int w = t >> 6, lane = t & 63;
  const int wr = (w >> 1)*32, wc = (w & 1)*32;
  const int fr = lane & 15, fk = lane >> 4;
  const int srow = t >> 2, scol = (t & 3)*8;

  v4f acc[2][2];
#pragma unroll
  for (int i = 0; i < 2; i++)
#pragma unroll
    for (int j = 0; j < 2; j++) acc[i][j] = (v4f){0.f,0.f,0.f,0.f};

  for (int k0 = 0; k0 < 256; k0 += 32) {
    __syncthreads();
    {
      int gm = m_base + srow;
      uint4 av = make_uint4(0u,0u,0u,0u);
      if (gm < N) av = loadpack8(x + (size_t)gm*256 + k0 + scol);
      *(uint4*)&As[srow*40 + scol] = av;
      uint4 bv = loadpack8(wpre + (size_t)(n_base + srow)*256 + k0 + scol);
      *(uint4*)&Bs[srow*40 + scol] = bv;
    }
    __syncthreads();
    v8s b0 = *(const v8s*)&Bs[(wc      + fr)*40 + fk*8];
    v8s b1 = *(const v8s*)&Bs[(wc + 16 + fr)*40 + fk*8];
#pragma unroll
    for (int mi = 0; mi < 2; mi++) {
      v8s a = *(const v8s*)&As[(wr + mi*16 + fr)*40 + fk*8];
      acc[mi][0] = __builtin_amdgcn_mfma_f32_16x16x32_bf16(a,b0,acc[mi][0],0,0,0);
      acc[mi][1] = __builtin_amdgcn_mfma_f32_16x16x32_bf16(a,b1,acc[mi][1],0,0,0);
    }
  }

  // ---- epilogue: GroupNorm in-register, yn -> ynL ----
#pragma unroll
  for (int nj = 0; nj < 2; nj++) {
    int col = n_base + wc + nj*16 + fr;
    float bpv = bpre[col];
    int gloc = (w & 1)*2 + nj;                  // group within tile 0..3
#pragma unroll
    for (int mi = 0; mi < 2; mi++) {
#pragma unroll
      for (int r = 0; r < 4; r++) {
        float yv = acc[mi][nj][r] + bpv;
        float s1 = rsum16(yv);
        float s2 = rsum16(yv*yv);
        float mu = s1 * 0.0625f;
        float var = fmaxf(s2*0.0625f - mu*mu, 0.f);
        float ynv = (yv - mu) * rsqrtf(var + GN_EPS);
        int row = wr + mi*16 + fk*4 + r;        // 0..63
        ynL[row*74 + gloc*16 + fr] = f2bf(ynv);
      }
    }
  }
  __syncthreads();   // MFMA LDS reads done; ynL published

  // ---- stage qkv weights for this tile's 4 groups (over As/Bs) ----
  {
    const float* srcs[3] = {wq, wk, wv};
#pragma unroll
    for (int tz = 0; tz < 3; tz++) {
      for (int i = t; i < 2048; i += 256) {
        int gi = i >> 9, rem = i & 511;
        wL[tz*2080 + gi*520 + rem] = srcs[tz][((size_t)(bn*4 + gi))*512 + rem];
      }
    }
  }
  __syncthreads();

  // ---- conv phase: wave w = group w, 64 lanes = 64 nodes, 1 pass ----
  u16* outs[3] = {qo, ko, vo};
  const int gl = w;                             // 4 waves, 4 groups
  const int g  = bn*4 + gl;
  {
    int nloc = lane;
    int node = m_base + nloc;
    if (node < N) {
      u32 yw[8];
#pragma unroll
      for (int j = 0; j < 8; j++)
        yw[j] = *(const u32*)&ynL[nloc*74 + gl*16 + j*2];
      float yn[16];
#pragma unroll
      for (int j = 0; j < 8; j++) { yn[2*j] = bflo(yw[j]); yn[2*j+1] = bfhi(yw[j]); }
#pragma unroll
      for (int tz = 0; tz < 3; tz++) {
#pragma unroll
        for (int s = 0; s < 2; s++) {
          u32 pk[8];
#pragma unroll
          for (int o = 0; o < 16; o++) {
            float d = dot16(yn, &wL[tz*2080 + gl*520 + (s*16 + o)*16]);
            if (tz < 2) d = __expf(d*0.25f);
            if (o & 1) pk[o>>1] |= (u32)f2bf(d) << 16;
            else       pk[o>>1]  = (u32)f2bf(d);
          }
          u16* dst = outs[tz] + (size_t)node*512 + g*32 + s*16;
          *(uint4*)dst       = make_uint4(pk[0],pk[1],pk[2],pk[3]);
          *(uint4*)(dst + 8) = make_uint4(pk[4],pk[5],pk[6],pk[7]);
        }
      }
    }
  }
}

// =====================================================================
// K3 (512 threads, fused, reduction-free): thread (nh, d) owns output
// row KV[nh][d][0:16] and k_sum[nh][d]; accumulates over ALL graph
// nodes. Phase 2: out1 = KV + xres; kv -> LDS bf16. Phase 3: att.
// =====================================================================
__global__ __launch_bounds__(512) void k_segatt(
    const u16* __restrict__ xk, const u16* __restrict__ xv,
    const u16* __restrict__ xq, const float* __restrict__ xres,
    const int* __restrict__ bounds,
    float* __restrict__ out1, u16* __restrict__ att, int N)
{
  __shared__ __align__(16) u16 kvs[32*280];     // 17.5 KB
  __shared__ float kss[32*17];                  // 2.2 KB
  const int b = blockIdx.x, t = threadIdx.x;
  const int lo = bounds[b], hi = bounds[b+1];
  const int nh = t >> 4, d = t & 15;

  float kv[16];
#pragma unroll
  for (int v = 0; v < 16; v++) kv[v] = 0.f;
  float ks = 0.f;

  const size_t koff = (size_t)nh*16 + d;
  const size_t voff = (size_t)nh*16;
  int node = lo;
  for (; node + 1 < hi; node += 2) {
    u16  ka  = xk[(size_t)node*512 + koff];
    uint4 Va0 = *(const uint4*)(xv + (size_t)node*512 + voff);
    uint4 Va1 = *(const uint4*)(xv + (size_t)node*512 + voff + 8);
    u16  kb  = xk[(size_t)(node+1)*512 + koff];
    uint4 Vb0 = *(const uint4*)(xv + (size_t)(node+1)*512 + voff);
    uint4 Vb1 = *(const uint4*)(xv + (size_t)(node+1)*512 + voff + 8);
    float k0 = bf1(ka), k1 = bf1(kb);
    float va[16], vb[16];
    unpack8(Va0, va); unpack8(Va1, va + 8);
    unpack8(Vb0, vb); unpack8(Vb1, vb + 8);
    ks += k0 + k1;
#pragma unroll
    for (int v = 0; v < 16; v++) {
      kv[v] = fmaf(k0, va[v], kv[v]);
      kv[v] = fmaf(k1, vb[v], kv[v]);
    }
  }
  if (node < hi) {
    u16  ka  = xk[(size_t)node*512 + koff];
    uint4 V0 = *(const uint4*)(xv + (size_t)node*512 + voff);
    uint4 V1 = *(const uint4*)(xv + (size_t)node*512 + voff + 8);
    float k0 = bf1(ka);
    float vf[16]; unpack8(V0, vf); unpack8(V1, vf + 8);
    ks += k0;
#pragma unroll
    for (int v = 0; v < 16; v++) kv[v] = fmaf(k0, vf[v], kv[v]);
  }

  kss[nh*17 + d] = ks;

  {
    size_t idx = ((size_t)(b*32 + nh)*16 + d)*16;
    const float* xp = xres + idx;
    float4 X0 = *(const float4*)xp;
    float4 X1 = *(const float4*)(xp + 4);
    float4 X2 = *(const float4*)(xp + 8);
    float4 X3 = *(const float4*)(xp + 12);
    float xf[16] = {X0.x,X0.y,X0.z,X0.w,X1.x,X1.y,X1.z,X1.w,
                    X2.x,X2.y,X2.z,X2.w,X3.x,X3.y,X3.z,X3.w};
    float o[16];
#pragma unroll
    for (int j = 0; j < 16; j++) o[j] = kv[j] + xf[j];
    float* op = out1 + idx;
    *(float4*)op        = make_float4(o[0],o[1],o[2],o[3]);
    *(float4*)(op + 4)  = make_float4(o[4],o[5],o[6],o[7]);
    *(float4*)(op + 8)  = make_float4(o[8],o[9],o[10],o[11]);
    *(float4*)(op + 12) = make_float4(o[12],o[13],o[14],o[15]);
    u16* lp = &kvs[nh*280 + d*16];
    *(uint4*)lp       = make_uint4(pack2(o[0],o[1]),  pack2(o[2],o[3]),
                                   pack2(o[4],o[5]),  pack2(o[6],o[7]));
    *(uint4*)(lp + 8) = make_uint4(pack2(o[8],o[9]),  pack2(o[10],o[11]),
                                   pack2(o[12],o[13]),pack2(o[14],o[15]));
  }
  __syncthreads();

  const int nh2 = t & 31, ns = t >> 5;   // ns 0..15
  for (int n0 = lo; n0 < hi; n0 += 16) {
    int nodei = n0 + ns;
    if (nodei >= hi) continue;
    const u16* qp = xq + (size_t)nodei*512 + nh2*16;
    uint4 Q0 = *(const uint4*)qp;
    uint4 Q1 = *(const uint4*)(qp + 8);
    float q[16]; unpack8(Q0, q); unpack8(Q1, q + 8);
    const float* ksp = &kss[nh2*17];
    float denom = 0.f;
#pragma unroll
    for (int i = 0; i < 16; i++) denom = fmaf(q[i], ksp[i], denom);
    float inv = 1.0f / fmaxf(denom, 1e-20f);
    float a[16];
#pragma unroll
    for (int v = 0; v < 16; v++) a[v] = 0.f;
    const u16* kvp = &kvs[nh2*280];
#pragma unroll
    for (int h = 0; h < 16; h++) {
      float qh = q[h] * inv;
      uint4 W0 = *(const uint4*)(kvp + h*16);
      uint4 W1 = *(const uint4*)(kvp + h*16 + 8);
      float wv2[16]; unpack8(W0, wv2); unpack8(W1, wv2 + 8);
#pragma unroll
      for (int v = 0; v < 16; v++) a[v] = fmaf(qh, wv2[v], a[v]);
    }
    u32 p[8];
#pragma unroll
    for (int j = 0; j < 8; j++) p[j] = pack2(a[2*j], a[2*j+1]);
    u16* dst = att + (size_t)nodei*512 + nh2*16;
    *(uint4*)dst       = make_uint4(p[0],p[1],p[2],p[3]);
    *(uint4*)(dst + 8) = make_uint4(p[4],p[5],p[6],p[7]);
  }
}

// =====================================================================
// K5 (MFMA): out0 = exp(log_scale) * (att @ w_post^T + b_post), K=512.
// Tile 128x64, XCD-swizzled block order (att-row L2 sharing).
// =====================================================================
__global__ __launch_bounds__(256) void k_post(
    const u16* __restrict__ att, const float* __restrict__ wpost,
    const float* __restrict__ bpost, const float* __restrict__ ls,
    float* __restrict__ out0, int N, int nbm)
{
  __shared__ __align__(16) u16 As[128*40];
  __shared__ __align__(16) u16 Bs[64*40];
  const int t = threadIdx.x;
  const int l  = xcd_remap(blockIdx.x, nbm*4);
  const int bm = l >> 2;
  const int bn = l & 3;
  const int m_base = bm*128, n_base = bn*64;
  const int w = t >> 6, lane = t & 63;
  const int wr = (w >> 1)*64, wc = (w & 1)*32;
  const int fr = lane & 15, fk = lane >> 4;
  const int arow = t >> 1, acol = (t & 1)*16;
  const int brow = t >> 2, bcol = (t & 3)*8;

  v4f acc[4][2];
#pragma unroll
  for (int i = 0; i < 4; i++)
#pragma unroll
    for (int j = 0; j < 2; j++) acc[i][j] = (v4f){0.f,0.f,0.f,0.f};

  for (int k0 = 0; k0 < 512; k0 += 32) {
    __syncthreads();
    {
      int gm = m_base + arow;
      uint4 a0 = make_uint4(0u,0u,0u,0u), a1 = make_uint4(0u,0u,0u,0u);
      if (gm < N) {
        a0 = *(const uint4*)(att + (size_t)gm*512 + k0 + acol);
        a1 = *(const uint4*)(att + (size_t)gm*512 + k0 + acol + 8);
      }
      *(uint4*)&As[arow*40 + acol]     = a0;
      *(uint4*)&As[arow*40 + acol + 8] = a1;
      uint4 bv = loadpack8(wpost + (size_t)(n_base + brow)*512 + k0 + bcol);
      *(uint4*)&Bs[brow*40 + bcol] = bv;
    }
    __syncthreads();
    v8s b0 = *(const v8s*)&Bs[(wc      + fr)*40 + fk*8];
    v8s b1 = *(const v8s*)&Bs[(wc + 16 + fr)*40 + fk*8];
#pragma unroll
    for (int mi = 0; mi < 4; mi++) {
      v8s a = *(const v8s*)&As[(wr + mi*16 + fr)*40 + fk*8];
      acc[mi][0] = __builtin_amdgcn_mfma_f32_16x16x32_bf16(a,b0,acc[mi][0],0,0,0);
      acc[mi][1] = __builtin_amdgcn_mfma_f32_16x16x32_bf16(a,b1,acc[mi][1],0,0,0);
    }
  }
#pragma unroll
  for (int nj = 0; nj < 2; nj++) {
    int col = n_base + wc + nj*16 + fr;
    float bpv = bpost[col];
    float e   = __expf(ls[col]);
#pragma unroll
    for (int mi = 0; mi < 4; mi++) {
#pragma unroll
      for (int r = 0; r < 4; r++) {
        int row = m_base + wr + mi*16 + fk*4 + r;
        if (row < N) out0[(size_t)row*256 + col] = e*(acc[mi][nj][r] + bpv);
      }
    }
  }
}

// =====================================================================
extern "C" void kernel_launch(void* const* d_in, const int* in_sizes, int n_in,
                              void* d_out, int out_size, void* d_ws, size_t ws_size,
                              hipStream_t stream)
{
  const float* x     = (const float*)d_in[0];
  const float* xres  = (const float*)d_in[1];
  const int*   batch = (const int*)d_in[2];
  const float* wpre  = (const float*)d_in[4];
  const float* bpre  = (const float*)d_in[5];
  const float* wq    = (const float*)d_in[6];
  const float* wk    = (const float*)d_in[7];
  const float* wv    = (const float*)d_in[8];
  const float* wpost = (const float*)d_in[9];
  const float* bpost = (const float*)d_in[10];
  const float* ls    = (const float*)d_in[11];

  const int N = in_sizes[0] / 256;     // 20000 nodes
  const int B = in_sizes[1] / 8192;    // 1024 graphs
  const int nbm1 = (N + 63) / 64;      // 313 row tiles (prefused, 64-row)
  const int nbm2 = (N + 127) / 128;    // 157 row tiles (post, 128-row)
  const int nchunk = (N + 255) / 256;  // 79 node chunks

  char* ws = (char*)d_ws;
  size_t off = 0;
  int*   flags  = (int*)(ws + off); off += 256;
  int*   bounds = (int*)(ws + off); off += ((size_t)B + 64) * 4;
  u16*   att    = (u16*)(ws + off);  off += (size_t)N * 1024;
  u16*   q      = (u16*)(ws + off);  off += (size_t)N * 1024;
  u16*   kten   = (u16*)(ws + off);  off += (size_t)N * 1024;
  u16*   vten   = (u16*)(ws + off);  off += (size_t)N * 1024;

  float* out0 = (float*)d_out;
  float* out1 = out0 + (size_t)N * 256;

  hipMemsetAsync(flags, 0, 4, stream);
  k_detect  <<<nchunk,        256, 0, stream>>>(batch, N, flags);
  k_bounds  <<<nchunk,        256, 0, stream>>>(batch, flags, N, B, bounds);
  k_prefused<<<nbm1 * 4,      256, 0, stream>>>(x, wpre, bpre, wq, wk, wv,
                                                q, kten, vten, N, nbm1);
  k_segatt  <<<B,             512, 0, stream>>>(kten, vten, q, xres, bounds,
                                                out1, att, N);
  k_post    <<<nbm2 * 4,      256, 0, stream>>>(att, wpost, bpost, ls, out0, N, nbm2);
}